// Round 6
// baseline (285.511 us; speedup 1.0000x reference)
//
#include <hip/hip_runtime.h>
#include <hip/hip_bf16.h>
#include <stdint.h>

#define T_TOK 2048
#define DIM   1024
#define HDIM  2048
#define NE    8
#define ROWS_PAD 4224   // 4096 routed rows + 128 pad for tile overrun

typedef __attribute__((ext_vector_type(8))) short bf16x8;
typedef __attribute__((ext_vector_type(4))) float f32x4;

__device__ __forceinline__ unsigned short f2bf(float f) {
    union { float f; unsigned int u; } v; v.f = f;
    unsigned int r = v.u + 0x7FFF + ((v.u >> 16) & 1);   // round-nearest-even
    return (unsigned short)(r >> 16);
}

__device__ __forceinline__ void gload16(const void* g, void* l) {
    __builtin_amdgcn_global_load_lds(
        (const __attribute__((address_space(1))) void*)g,
        (__attribute__((address_space(3))) void*)l, 16, 0, 0);
}

// ---------------- transpose + fp32->bf16 convert: in[b][R][C] -> out[b][C][R]
__global__ void transpose_cvt(const float* __restrict__ in, unsigned short* __restrict__ out,
                              int R, int C) {
    __shared__ float tile[32][33];
    int b = blockIdx.z;
    int bx = blockIdx.x, by = blockIdx.y;
    int tx = threadIdx.x & 31, ty = threadIdx.x >> 5;
    const float* ip = in + (size_t)b * R * C;
    unsigned short* op = out + (size_t)b * R * C;
#pragma unroll
    for (int i = 0; i < 4; ++i) {
        int r = by * 32 + ty + i * 8;
        tile[ty + i * 8][tx] = ip[(size_t)r * C + bx * 32 + tx];
    }
    __syncthreads();
#pragma unroll
    for (int i = 0; i < 4; ++i) {
        int oc = bx * 32 + ty + i * 8;   // row of out (= col of in)
        int orw = by * 32 + tx;          // col of out (= row of in)
        op[(size_t)oc * R + orw] = f2bf(tile[tx][ty + i * 8]);
    }
}

// ---------------- router: logits = x @ rw, top-2 softmax, counts
__global__ void router_kernel(const float* __restrict__ x, const float* __restrict__ rw,
                              int* __restrict__ counts, int* __restrict__ top_idx,
                              float* __restrict__ top_w) {
    int wid = (blockIdx.x * blockDim.x + threadIdx.x) >> 6;
    int lane = threadIdx.x & 63;
    if (wid >= T_TOK) return;
    float acc[NE];
#pragma unroll
    for (int e = 0; e < NE; ++e) acc[e] = 0.f;
    const float* xr = x + (size_t)wid * DIM;
    for (int i = lane; i < DIM; i += 64) {
        float xv = xr[i];
        const float* wr = rw + (size_t)i * NE;
#pragma unroll
        for (int e = 0; e < NE; ++e) acc[e] += xv * wr[e];
    }
#pragma unroll
    for (int off = 32; off; off >>= 1) {
#pragma unroll
        for (int e = 0; e < NE; ++e) acc[e] += __shfl_xor(acc[e], off, 64);
    }
    if (lane == 0) {
        float v0 = -1e30f, v1 = -1e30f; int i0 = 0, i1 = 0;
#pragma unroll
        for (int e = 0; e < NE; ++e) {
            float v = acc[e];
            if (v > v0) { v1 = v0; i1 = i0; v0 = v; i0 = e; }
            else if (v > v1) { v1 = v; i1 = e; }
        }
        float e1 = __expf(v1 - v0);
        float s = 1.f + e1;
        top_idx[wid * 2]     = i0;
        top_idx[wid * 2 + 1] = i1;
        top_w[wid * 2]     = 1.f / s;
        top_w[wid * 2 + 1] = e1 / s;
        atomicAdd(&counts[i0], 1);
        atomicAdd(&counts[i1], 1);
    }
}

// ---------------- tiny exclusive scan of 8 counts
__global__ void scan_kernel(const int* __restrict__ counts, int* __restrict__ offsets,
                            int* __restrict__ cursors) {
    if (threadIdx.x == 0) {
        int run = 0;
        for (int e = 0; e < NE; ++e) { offsets[e] = run; cursors[e] = run; run += counts[e]; }
    }
}

// ---------------- gather: pack each token's row (bf16) into its 2 experts' segments
__global__ void gather_kernel(const float* __restrict__ x, const int* __restrict__ top_idx,
                              const float* __restrict__ top_w, int* __restrict__ cursors,
                              int* __restrict__ row_tok, float* __restrict__ row_w,
                              unsigned short* __restrict__ Abuf) {
    int t = blockIdx.x;
    __shared__ int pos[2];
    if (threadIdx.x < 2) {
        int k = threadIdx.x;
        int e = top_idx[t * 2 + k];
        int p = atomicAdd(&cursors[e], 1);
        pos[k] = p;
        row_tok[p] = t;
        row_w[p] = top_w[t * 2 + k];
    }
    __syncthreads();
    const float4* xr = (const float4*)(x + (size_t)t * DIM);
    float4 v = xr[threadIdx.x];
    ushort4 b;
    b.x = f2bf(v.x); b.y = f2bf(v.y); b.z = f2bf(v.z); b.w = f2bf(v.w);
    ushort4* A4 = (ushort4*)Abuf;
    A4[(size_t)pos[0] * (DIM / 4) + threadIdx.x] = b;
    A4[(size_t)pos[1] * (DIM / 4) + threadIdx.x] = b;
}

// ---------------- GEMM1: hidden = silu(A @ WgT^T) * (A @ WuT^T), per expert
// 3-buffer depth-2 prefetch, counted vmcnt + raw s_barrier, BK=32, XOR swizzle.
__global__ __launch_bounds__(256, 2)
void gemm1_kernel(const unsigned short* __restrict__ Abuf,
                  const unsigned short* __restrict__ WgT,
                  const unsigned short* __restrict__ WuT,
                  unsigned short* __restrict__ Hbuf,
                  const int* __restrict__ offsets, const int* __restrict__ counts) {
    const int e = blockIdx.z;
    const int cnt = counts[e];
    const int mtile = blockIdx.y;
    if (mtile * 128 >= cnt) return;
    const int n0 = blockIdx.x * 128;
    const int row0 = offsets[e] + mtile * 128;

    __shared__ unsigned short As[3][128 * 32];   // 24 KB
    __shared__ unsigned short Bg[3][128 * 32];   // 24 KB
    __shared__ unsigned short Bu[3][128 * 32];   // 24 KB  (72 KB total -> 2 blocks/CU)

    const int tid = threadIdx.x;
    const int lane = tid & 63;
    const int wave = tid >> 6;
    const int wm = wave >> 1, wn = wave & 1;

    f32x4 accg[4][4], accu[4][4];
#pragma unroll
    for (int i = 0; i < 4; ++i)
#pragma unroll
        for (int j = 0; j < 4; ++j) {
            accg[i][j] = (f32x4){0.f, 0.f, 0.f, 0.f};
            accu[i][j] = (f32x4){0.f, 0.f, 0.f, 0.f};
        }

    // staging: 2 issues x 3 arrays = 6 gload16 per thread per stage
    const int srow0 = tid >> 2;         // row within 64-row half (+i*64)
    const int sc0 = tid & 3;            // LDS 16B-chunk within 64B row
    const unsigned short* Aab = Abuf + (size_t)row0 * DIM;
    const unsigned short* Bgb = WgT + (size_t)e * HDIM * DIM + (size_t)n0 * DIM;
    const unsigned short* Bub = WuT + (size_t)e * HDIM * DIM + (size_t)n0 * DIM;

    auto stage = [&](int buf, int kt) {
#pragma unroll
        for (int i = 0; i < 2; ++i) {
            int row = i * 64 + srow0;
            int csrc = sc0 ^ ((row >> 1) & 3);            // inverse swizzle on source
            size_t go = (size_t)row * DIM + kt + csrc * 8;
            int lo = (i * 256 + tid) * 8;                 // linear LDS dest (shorts)
            gload16(Aab + go, &As[buf][lo]);
            gload16(Bgb + go, &Bg[buf][lo]);
            gload16(Bub + go, &Bu[buf][lo]);
        }
    };

    const int rsel = lane & 15;
    const int csrcf = lane >> 4;        // fragment k-chunk (0..3)

    const int NS = DIM / 32;            // 32 K-steps
    stage(0, 0);
    stage(1, 32);
    int cur = 0;
    for (int s = 0; s < NS; ++s) {
        // retire the oldest stage (6 loads); leave the depth-1 prefetch (6) in flight
        if (s + 1 < NS) { asm volatile("s_waitcnt vmcnt(6)" ::: "memory"); }
        else            { asm volatile("s_waitcnt vmcnt(0)" ::: "memory"); }
        __builtin_amdgcn_s_barrier();
        if (s + 2 < NS) {
            int pb = cur + 2; if (pb >= 3) pb -= 3;
            stage(pb, (s + 2) * 32);
        }
        const unsigned short* Ac = As[cur];
        const unsigned short* Bgc = Bg[cur];
        const unsigned short* Buc = Bu[cur];
        bf16x8 af[4], bg[4], bu[4];
#pragma unroll
        for (int i = 0; i < 4; ++i) {
            int ra = wm * 64 + i * 16 + rsel;
            af[i] = *(const bf16x8*)&Ac[ra * 32 + (csrcf ^ ((ra >> 1) & 3)) * 8];
            int rb = wn * 64 + i * 16 + rsel;
            int cb = (csrcf ^ ((rb >> 1) & 3)) * 8;
            bg[i] = *(const bf16x8*)&Bgc[rb * 32 + cb];
            bu[i] = *(const bf16x8*)&Buc[rb * 32 + cb];
        }
#pragma unroll
        for (int i = 0; i < 4; ++i)
#pragma unroll
            for (int j = 0; j < 4; ++j) {
                accg[i][j] = __builtin_amdgcn_mfma_f32_16x16x32_bf16(af[i], bg[j], accg[i][j], 0, 0, 0);
                accu[i][j] = __builtin_amdgcn_mfma_f32_16x16x32_bf16(af[i], bu[j], accu[i][j], 0, 0, 0);
            }
        ++cur; if (cur == 3) cur = 0;
    }

    const int c = lane & 15, rbase = (lane >> 4) * 4;
    const int obase = offsets[e];
#pragma unroll
    for (int i = 0; i < 4; ++i) {
#pragma unroll
        for (int r = 0; r < 4; ++r) {
            int lrow = mtile * 128 + wm * 64 + i * 16 + rbase + r;
            if (lrow < cnt) {
                size_t orow = (size_t)(obase + lrow);
#pragma unroll
                for (int j = 0; j < 4; ++j) {
                    float g = accg[i][j][r], u = accu[i][j][r];
                    float h = g * u / (1.f + __expf(-g));
                    Hbuf[orow * HDIM + n0 + wn * 64 + j * 16 + c] = f2bf(h);
                }
            }
        }
    }
}

// ---------------- GEMM2: y[tok] += w * (hidden @ WdT^T)
// 3-buffer depth-2 prefetch, counted vmcnt + raw s_barrier, BK=32, K split x2.
__global__ __launch_bounds__(256, 3)
void gemm2_kernel(const unsigned short* __restrict__ Hbuf,
                  const unsigned short* __restrict__ WdT,
                  float* __restrict__ y,
                  const int* __restrict__ offsets, const int* __restrict__ counts,
                  const int* __restrict__ row_tok, const float* __restrict__ row_w) {
    const int e = blockIdx.z >> 1;
    const int kc = blockIdx.z & 1;
    const int cnt = counts[e];
    const int mtile = blockIdx.y;
    if (mtile * 128 >= cnt) return;
    const int n0 = blockIdx.x * 128;
    const int row0 = offsets[e] + mtile * 128;

    __shared__ unsigned short As[3][128 * 32];   // 24 KB
    __shared__ unsigned short Bs[3][128 * 32];   // 24 KB  (48 KB -> 3 blocks/CU)

    const int tid = threadIdx.x;
    const int lane = tid & 63;
    const int wave = tid >> 6;
    const int wm = wave >> 1, wn = wave & 1;

    f32x4 acc[4][4];
#pragma unroll
    for (int i = 0; i < 4; ++i)
#pragma unroll
        for (int j = 0; j < 4; ++j) acc[i][j] = (f32x4){0.f, 0.f, 0.f, 0.f};

    // staging: 2 issues x 2 arrays = 4 gload16 per thread per stage
    const int srow0 = tid >> 2;
    const int sc0 = tid & 3;
    const unsigned short* Aab = Hbuf + (size_t)row0 * HDIM;
    const unsigned short* Bbb = WdT + (size_t)e * DIM * HDIM + (size_t)n0 * HDIM;

    auto stage = [&](int buf, int kt) {
#pragma unroll
        for (int i = 0; i < 2; ++i) {
            int row = i * 64 + srow0;
            int csrc = sc0 ^ ((row >> 1) & 3);
            size_t go = (size_t)row * HDIM + kt + csrc * 8;
            int lo = (i * 256 + tid) * 8;
            gload16(Aab + go, &As[buf][lo]);
            gload16(Bbb + go, &Bs[buf][lo]);
        }
    };

    const int rsel = lane & 15;
    const int csrcf = lane >> 4;

    const int kbeg = kc * (HDIM / 2);
    const int NS = (HDIM / 2) / 32;     // 32 K-steps

    stage(0, kbeg);
    stage(1, kbeg + 32);
    int cur = 0;
    for (int s = 0; s < NS; ++s) {
        if (s + 1 < NS) { asm volatile("s_waitcnt vmcnt(4)" ::: "memory"); }
        else            { asm volatile("s_waitcnt vmcnt(0)" ::: "memory"); }
        __builtin_amdgcn_s_barrier();
        if (s + 2 < NS) {
            int pb = cur + 2; if (pb >= 3) pb -= 3;
            stage(pb, kbeg + (s + 2) * 32);
        }
        const unsigned short* Ac = As[cur];
        const unsigned short* Bc = Bs[cur];
        bf16x8 af[4], bf[4];
#pragma unroll
        for (int i = 0; i < 4; ++i) {
            int ra = wm * 64 + i * 16 + rsel;
            af[i] = *(const bf16x8*)&Ac[ra * 32 + (csrcf ^ ((ra >> 1) & 3)) * 8];
            int rb = wn * 64 + i * 16 + rsel;
            bf[i] = *(const bf16x8*)&Bc[rb * 32 + (csrcf ^ ((rb >> 1) & 3)) * 8];
        }
#pragma unroll
        for (int i = 0; i < 4; ++i)
#pragma unroll
            for (int j = 0; j < 4; ++j)
                acc[i][j] = __builtin_amdgcn_mfma_f32_16x16x32_bf16(af[i], bf[j], acc[i][j], 0, 0, 0);
        ++cur; if (cur == 3) cur = 0;
    }

    const int c = lane & 15, rbase = (lane >> 4) * 4;
    const int obase = offsets[e];
#pragma unroll
    for (int i = 0; i < 4; ++i) {
#pragma unroll
        for (int r = 0; r < 4; ++r) {
            int lrow = mtile * 128 + wm * 64 + i * 16 + rbase + r;
            if (lrow < cnt) {
                int grow = obase + lrow;
                int tok = row_tok[grow];
                float w = row_w[grow];
#pragma unroll
                for (int j = 0; j < 4; ++j) {
                    atomicAdd(&y[(size_t)tok * DIM + n0 + wn * 64 + j * 16 + c], w * acc[i][j][r]);
                }
            }
        }
    }
}

extern "C" void kernel_launch(void* const* d_in, const int* in_sizes, int n_in,
                              void* d_out, int out_size, void* d_ws, size_t ws_size,
                              hipStream_t stream) {
    const float* x  = (const float*)d_in[0];
    const float* rw = (const float*)d_in[1];
    const float* gw = (const float*)d_in[2];
    const float* uw = (const float*)d_in[3];
    const float* dw = (const float*)d_in[4];
    float* y = (float*)d_out;

    char* ws = (char*)d_ws;
    int*   counts  = (int*)(ws + 0);
    int*   cursors = (int*)(ws + 32);
    int*   offsets = (int*)(ws + 64);
    int*   top_idx = (int*)(ws + 128);
    float* top_w   = (float*)(ws + 128 + 16384);
    int*   row_tok = (int*)(ws + 128 + 32768);
    float* row_w   = (float*)(ws + 128 + 32768 + 16896);
    size_t off = 128 + 32768 + 2 * 16896;
    off = (off + 255) & ~(size_t)255;
    unsigned short* Abuf = (unsigned short*)(ws + off); off += (size_t)ROWS_PAD * DIM * 2;
    unsigned short* Hbuf = (unsigned short*)(ws + off); off += (size_t)ROWS_PAD * HDIM * 2;
    unsigned short* WgT  = (unsigned short*)(ws + off); off += (size_t)NE * DIM * HDIM * 2;
    unsigned short* WuT  = (unsigned short*)(ws + off); off += (size_t)NE * DIM * HDIM * 2;
    unsigned short* WdT  = (unsigned short*)(ws + off); off += (size_t)NE * DIM * HDIM * 2;
    if (ws_size < off) return;  // workspace too small: fail loudly (zero output)

    hipMemsetAsync(counts, 0, 32, stream);
    hipMemsetAsync(d_out, 0, (size_t)out_size * 4, stream);

    // weight transpose+convert (independent of routing)
    transpose_cvt<<<dim3(HDIM / 32, DIM / 32, NE), 256, 0, stream>>>(gw, WgT, DIM, HDIM);
    transpose_cvt<<<dim3(HDIM / 32, DIM / 32, NE), 256, 0, stream>>>(uw, WuT, DIM, HDIM);
    transpose_cvt<<<dim3(DIM / 32, HDIM / 32, NE), 256, 0, stream>>>(dw, WdT, HDIM, DIM);

    router_kernel<<<T_TOK / 4, 256, 0, stream>>>(x, rw, counts, top_idx, top_w);
    scan_kernel<<<1, 64, 0, stream>>>(counts, offsets, cursors);
    gather_kernel<<<T_TOK, 256, 0, stream>>>(x, top_idx, top_w, cursors, row_tok, row_w, Abuf);

    gemm1_kernel<<<dim3(HDIM / 128, 16, NE), 256, 0, stream>>>(Abuf, WgT, WuT, Hbuf, offsets, counts);
    gemm2_kernel<<<dim3(DIM / 128, 16, NE * 2), 256, 0, stream>>>(Hbuf, WdT, y, offsets, counts, row_tok, row_w);
}

// Round 7
// 278.781 us; speedup vs baseline: 1.0241x; 1.0241x over previous
//
#include <hip/hip_runtime.h>
#include <hip/hip_bf16.h>
#include <stdint.h>

#define T_TOK 2048
#define DIM   1024
#define HDIM  2048
#define NE    8
#define ROWS_PAD 4224   // 4096 routed rows + 128 pad for tile overrun
#define TSLOTS 40       // max live (expert,mtile) pairs: 32 + 7 = 39

typedef __attribute__((ext_vector_type(8))) short bf16x8;
typedef __attribute__((ext_vector_type(4))) float f32x4;

__device__ __forceinline__ unsigned short f2bf(float f) {
    union { float f; unsigned int u; } v; v.f = f;
    unsigned int r = v.u + 0x7FFF + ((v.u >> 16) & 1);   // round-nearest-even
    return (unsigned short)(r >> 16);
}

__device__ __forceinline__ void gload16(const void* g, void* l) {
    __builtin_amdgcn_global_load_lds(
        (const __attribute__((address_space(1))) void*)g,
        (__attribute__((address_space(3))) void*)l, 16, 0, 0);
}

// ---------------- transpose + fp32->bf16 convert: in[b][R][C] -> out[b][C][R]
__global__ void transpose_cvt(const float* __restrict__ in, unsigned short* __restrict__ out,
                              int R, int C) {
    __shared__ float tile[32][33];
    int b = blockIdx.z;
    int bx = blockIdx.x, by = blockIdx.y;
    int tx = threadIdx.x & 31, ty = threadIdx.x >> 5;
    const float* ip = in + (size_t)b * R * C;
    unsigned short* op = out + (size_t)b * R * C;
#pragma unroll
    for (int i = 0; i < 4; ++i) {
        int r = by * 32 + ty + i * 8;
        tile[ty + i * 8][tx] = ip[(size_t)r * C + bx * 32 + tx];
    }
    __syncthreads();
#pragma unroll
    for (int i = 0; i < 2; ++i) {
        int oc = i * 16 + (threadIdx.x >> 4);     // col of in = row of out (0..31)
        int orw2 = (threadIdx.x & 15) * 2;        // row of in = col of out, pair
        ushort2 v;
        v.x = f2bf(tile[orw2][oc]);
        v.y = f2bf(tile[orw2 + 1][oc]);
        *(ushort2*)&op[(size_t)(bx * 32 + oc) * R + by * 32 + orw2] = v;
    }
}

// ---------------- router: logits = x @ rw, top-2 softmax, counts
__global__ void router_kernel(const float* __restrict__ x, const float* __restrict__ rw,
                              int* __restrict__ counts, int* __restrict__ top_idx,
                              float* __restrict__ top_w) {
    int wid = (blockIdx.x * blockDim.x + threadIdx.x) >> 6;
    int lane = threadIdx.x & 63;
    if (wid >= T_TOK) return;
    float acc[NE];
#pragma unroll
    for (int e = 0; e < NE; ++e) acc[e] = 0.f;
    const float* xr = x + (size_t)wid * DIM;
    for (int i = lane; i < DIM; i += 64) {
        float xv = xr[i];
        const float* wr = rw + (size_t)i * NE;
#pragma unroll
        for (int e = 0; e < NE; ++e) acc[e] += xv * wr[e];
    }
#pragma unroll
    for (int off = 32; off; off >>= 1) {
#pragma unroll
        for (int e = 0; e < NE; ++e) acc[e] += __shfl_xor(acc[e], off, 64);
    }
    if (lane == 0) {
        float v0 = -1e30f, v1 = -1e30f; int i0 = 0, i1 = 0;
#pragma unroll
        for (int e = 0; e < NE; ++e) {
            float v = acc[e];
            if (v > v0) { v1 = v0; i1 = i0; v0 = v; i0 = e; }
            else if (v > v1) { v1 = v; i1 = e; }
        }
        float e1 = __expf(v1 - v0);
        float s = 1.f + e1;
        top_idx[wid * 2]     = i0;
        top_idx[wid * 2 + 1] = i1;
        top_w[wid * 2]     = 1.f / s;
        top_w[wid * 2 + 1] = e1 / s;
        atomicAdd(&counts[i0], 1);
        atomicAdd(&counts[i1], 1);
    }
}

// ---------------- scan + compact tile list (holes only at the tail)
__global__ void scan_kernel(const int* __restrict__ counts, int* __restrict__ offsets,
                            int* __restrict__ cursors,
                            int* __restrict__ tl_e, int* __restrict__ tl_m) {
    if (threadIdx.x == 0) {
        int run = 0;
        for (int e = 0; e < NE; ++e) { offsets[e] = run; cursors[e] = run; run += counts[e]; }
        int n = 0;
        for (int e = 0; e < NE; ++e) {
            int mt = (counts[e] + 127) >> 7;
            for (int m = 0; m < mt && n < 64; ++m) { tl_e[n] = e; tl_m[n] = m; ++n; }
        }
        for (; n < 64; ++n) tl_e[n] = -1;
    }
}

// ---------------- gather: pack each token's row (bf16) into its 2 experts' segments
__global__ void gather_kernel(const float* __restrict__ x, const int* __restrict__ top_idx,
                              const float* __restrict__ top_w, int* __restrict__ cursors,
                              int* __restrict__ row_tok, float* __restrict__ row_w,
                              unsigned short* __restrict__ Abuf) {
    int t = blockIdx.x;
    __shared__ int pos[2];
    if (threadIdx.x < 2) {
        int k = threadIdx.x;
        int e = top_idx[t * 2 + k];
        int p = atomicAdd(&cursors[e], 1);
        pos[k] = p;
        row_tok[p] = t;
        row_w[p] = top_w[t * 2 + k];
    }
    __syncthreads();
    const float4* xr = (const float4*)(x + (size_t)t * DIM);
    float4 v = xr[threadIdx.x];
    ushort4 b;
    b.x = f2bf(v.x); b.y = f2bf(v.y); b.z = f2bf(v.z); b.w = f2bf(v.w);
    ushort4* A4 = (ushort4*)Abuf;
    A4[(size_t)pos[0] * (DIM / 4) + threadIdx.x] = b;
    A4[(size_t)pos[1] * (DIM / 4) + threadIdx.x] = b;
}

// ---------------- GEMM1: hidden = silu(A @ WgT^T) * (A @ WuT^T), per expert
// 2-phase double-buffered, BK=32, XOR-swizzled LDS, compact tile-list grid.
__global__ __launch_bounds__(256, 2)
void gemm1_kernel(const unsigned short* __restrict__ Abuf,
                  const unsigned short* __restrict__ WgT,
                  const unsigned short* __restrict__ WuT,
                  unsigned short* __restrict__ Hbuf,
                  const int* __restrict__ offsets, const int* __restrict__ counts,
                  const int* __restrict__ tl_e, const int* __restrict__ tl_m) {
    const int slot = blockIdx.y;
    const int e = tl_e[slot];
    if (e < 0) return;
    const int mtile = tl_m[slot];
    const int cnt = counts[e];
    const int n0 = blockIdx.x * 128;
    const int row0 = offsets[e] + mtile * 128;

    __shared__ unsigned short As[2][128 * 32];
    __shared__ unsigned short Bg[2][128 * 32];
    __shared__ unsigned short Bu[2][128 * 32];   // 48 KB total -> 3 blocks/CU

    const int tid = threadIdx.x;
    const int lane = tid & 63;
    const int wave = tid >> 6;
    const int wm = wave >> 1, wn = wave & 1;

    f32x4 accg[4][4], accu[4][4];
#pragma unroll
    for (int i = 0; i < 4; ++i)
#pragma unroll
        for (int j = 0; j < 4; ++j) {
            accg[i][j] = (f32x4){0.f, 0.f, 0.f, 0.f};
            accu[i][j] = (f32x4){0.f, 0.f, 0.f, 0.f};
        }

    // staging: 2 issues x 256 threads x 16B = 8 KB per array per K-step
    const int srow0 = tid >> 2;         // row within 64-row half (+i*64)
    const int sc0 = tid & 3;            // LDS 16B-chunk within 64B row
    const unsigned short* Aab = Abuf + (size_t)row0 * DIM;
    const unsigned short* Bgb = WgT + (size_t)e * HDIM * DIM + (size_t)n0 * DIM;
    const unsigned short* Bub = WuT + (size_t)e * HDIM * DIM + (size_t)n0 * DIM;

    auto stage = [&](int buf, int kt) {
#pragma unroll
        for (int i = 0; i < 2; ++i) {
            int row = i * 64 + srow0;
            int csrc = sc0 ^ ((row >> 1) & 3);            // inverse swizzle on source
            size_t go = (size_t)row * DIM + kt + csrc * 8;
            int lo = (i * 256 + tid) * 8;                 // linear LDS dest (shorts)
            gload16(Aab + go, &As[buf][lo]);
            gload16(Bgb + go, &Bg[buf][lo]);
            gload16(Bub + go, &Bu[buf][lo]);
        }
    };

    const int rsel = lane & 15;
    const int csrcf = lane >> 4;        // fragment k-chunk (0..3)

    stage(0, 0);
    int cur = 0;
    for (int kt = 0; kt < DIM; kt += 32) {
        __syncthreads();                 // buf[cur] staged
        if (kt + 32 < DIM) stage(cur ^ 1, kt + 32);
        const unsigned short* Ac = As[cur];
        const unsigned short* Bgc = Bg[cur];
        const unsigned short* Buc = Bu[cur];
        bf16x8 af[4], bg[4], bu[4];
#pragma unroll
        for (int i = 0; i < 4; ++i) {
            int ra = wm * 64 + i * 16 + rsel;
            af[i] = *(const bf16x8*)&Ac[ra * 32 + (csrcf ^ ((ra >> 1) & 3)) * 8];
            int rb = wn * 64 + i * 16 + rsel;
            int cb = (csrcf ^ ((rb >> 1) & 3)) * 8;
            bg[i] = *(const bf16x8*)&Bgc[rb * 32 + cb];
            bu[i] = *(const bf16x8*)&Buc[rb * 32 + cb];
        }
#pragma unroll
        for (int i = 0; i < 4; ++i)
#pragma unroll
            for (int j = 0; j < 4; ++j) {
                accg[i][j] = __builtin_amdgcn_mfma_f32_16x16x32_bf16(af[i], bg[j], accg[i][j], 0, 0, 0);
                accu[i][j] = __builtin_amdgcn_mfma_f32_16x16x32_bf16(af[i], bu[j], accu[i][j], 0, 0, 0);
            }
        cur ^= 1;
    }

    const int c = lane & 15, rbase = (lane >> 4) * 4;
    const int obase = offsets[e];
#pragma unroll
    for (int i = 0; i < 4; ++i) {
#pragma unroll
        for (int r = 0; r < 4; ++r) {
            int lrow = mtile * 128 + wm * 64 + i * 16 + rbase + r;
            if (lrow < cnt) {
                size_t orow = (size_t)(obase + lrow);
#pragma unroll
                for (int j = 0; j < 4; ++j) {
                    float g = accg[i][j][r], u = accu[i][j][r];
                    float h = g * u / (1.f + __expf(-g));
                    Hbuf[orow * HDIM + n0 + wn * 64 + j * 16 + c] = f2bf(h);
                }
            }
        }
    }
}

// ---------------- GEMM2: y[tok] += w * (hidden @ WdT^T)
// 3-buffer depth-2 prefetch, counted vmcnt + raw s_barrier, BK=32, K split x2,
// compact tile-list grid.
__global__ __launch_bounds__(256, 3)
void gemm2_kernel(const unsigned short* __restrict__ Hbuf,
                  const unsigned short* __restrict__ WdT,
                  float* __restrict__ y,
                  const int* __restrict__ offsets, const int* __restrict__ counts,
                  const int* __restrict__ row_tok, const float* __restrict__ row_w,
                  const int* __restrict__ tl_e, const int* __restrict__ tl_m) {
    const int slot = blockIdx.y;
    const int e = tl_e[slot];
    if (e < 0) return;
    const int mtile = tl_m[slot];
    const int kc = blockIdx.z;
    const int cnt = counts[e];
    const int n0 = blockIdx.x * 128;
    const int row0 = offsets[e] + mtile * 128;

    __shared__ unsigned short As[3][128 * 32];   // 24 KB
    __shared__ unsigned short Bs[3][128 * 32];   // 24 KB  (48 KB -> 3 blocks/CU)

    const int tid = threadIdx.x;
    const int lane = tid & 63;
    const int wave = tid >> 6;
    const int wm = wave >> 1, wn = wave & 1;

    f32x4 acc[4][4];
#pragma unroll
    for (int i = 0; i < 4; ++i)
#pragma unroll
        for (int j = 0; j < 4; ++j) acc[i][j] = (f32x4){0.f, 0.f, 0.f, 0.f};

    // staging: 2 issues x 2 arrays = 4 gload16 per thread per stage
    const int srow0 = tid >> 2;
    const int sc0 = tid & 3;
    const unsigned short* Aab = Hbuf + (size_t)row0 * HDIM;
    const unsigned short* Bbb = WdT + (size_t)e * DIM * HDIM + (size_t)n0 * HDIM;

    auto stage = [&](int buf, int kt) {
#pragma unroll
        for (int i = 0; i < 2; ++i) {
            int row = i * 64 + srow0;
            int csrc = sc0 ^ ((row >> 1) & 3);
            size_t go = (size_t)row * HDIM + kt + csrc * 8;
            int lo = (i * 256 + tid) * 8;
            gload16(Aab + go, &As[buf][lo]);
            gload16(Bbb + go, &Bs[buf][lo]);
        }
    };

    const int rsel = lane & 15;
    const int csrcf = lane >> 4;

    const int kbeg = kc * (HDIM / 2);
    const int NS = (HDIM / 2) / 32;     // 32 K-steps

    stage(0, kbeg);
    stage(1, kbeg + 32);
    int cur = 0;
    for (int s = 0; s < NS; ++s) {
        if (s + 1 < NS) { asm volatile("s_waitcnt vmcnt(4)" ::: "memory"); }
        else            { asm volatile("s_waitcnt vmcnt(0)" ::: "memory"); }
        __builtin_amdgcn_s_barrier();
        if (s + 2 < NS) {
            int pb = cur + 2; if (pb >= 3) pb -= 3;
            stage(pb, kbeg + (s + 2) * 32);
        }
        const unsigned short* Ac = As[cur];
        const unsigned short* Bc = Bs[cur];
        bf16x8 af[4], bf[4];
#pragma unroll
        for (int i = 0; i < 4; ++i) {
            int ra = wm * 64 + i * 16 + rsel;
            af[i] = *(const bf16x8*)&Ac[ra * 32 + (csrcf ^ ((ra >> 1) & 3)) * 8];
            int rb = wn * 64 + i * 16 + rsel;
            bf[i] = *(const bf16x8*)&Bc[rb * 32 + (csrcf ^ ((rb >> 1) & 3)) * 8];
        }
#pragma unroll
        for (int i = 0; i < 4; ++i)
#pragma unroll
            for (int j = 0; j < 4; ++j)
                acc[i][j] = __builtin_amdgcn_mfma_f32_16x16x32_bf16(af[i], bf[j], acc[i][j], 0, 0, 0);
        ++cur; if (cur == 3) cur = 0;
    }

    const int c = lane & 15, rbase = (lane >> 4) * 4;
    const int obase = offsets[e];
#pragma unroll
    for (int i = 0; i < 4; ++i) {
#pragma unroll
        for (int r = 0; r < 4; ++r) {
            int lrow = mtile * 128 + wm * 64 + i * 16 + rbase + r;
            if (lrow < cnt) {
                int grow = obase + lrow;
                int tok = row_tok[grow];
                float w = row_w[grow];
#pragma unroll
                for (int j = 0; j < 4; ++j) {
                    atomicAdd(&y[(size_t)tok * DIM + n0 + wn * 64 + j * 16 + c], w * acc[i][j][r]);
                }
            }
        }
    }
}

extern "C" void kernel_launch(void* const* d_in, const int* in_sizes, int n_in,
                              void* d_out, int out_size, void* d_ws, size_t ws_size,
                              hipStream_t stream) {
    const float* x  = (const float*)d_in[0];
    const float* rw = (const float*)d_in[1];
    const float* gw = (const float*)d_in[2];
    const float* uw = (const float*)d_in[3];
    const float* dw = (const float*)d_in[4];
    float* y = (float*)d_out;

    char* ws = (char*)d_ws;
    int*   counts  = (int*)(ws + 0);
    int*   cursors = (int*)(ws + 32);
    int*   offsets = (int*)(ws + 64);
    int*   top_idx = (int*)(ws + 128);
    float* top_w   = (float*)(ws + 128 + 16384);
    int*   row_tok = (int*)(ws + 128 + 32768);
    float* row_w   = (float*)(ws + 128 + 32768 + 16896);
    int*   tl_e    = (int*)(ws + 128 + 32768 + 2 * 16896);
    int*   tl_m    = (int*)(ws + 128 + 32768 + 2 * 16896 + 256);
    size_t off = 128 + 32768 + 2 * 16896 + 512;
    off = (off + 255) & ~(size_t)255;
    unsigned short* Abuf = (unsigned short*)(ws + off); off += (size_t)ROWS_PAD * DIM * 2;
    unsigned short* Hbuf = (unsigned short*)(ws + off); off += (size_t)ROWS_PAD * HDIM * 2;
    unsigned short* WgT  = (unsigned short*)(ws + off); off += (size_t)NE * DIM * HDIM * 2;
    unsigned short* WuT  = (unsigned short*)(ws + off); off += (size_t)NE * DIM * HDIM * 2;
    unsigned short* WdT  = (unsigned short*)(ws + off); off += (size_t)NE * DIM * HDIM * 2;
    if (ws_size < off) return;  // workspace too small: fail loudly (zero output)

    hipMemsetAsync(counts, 0, 32, stream);
    hipMemsetAsync(d_out, 0, (size_t)out_size * 4, stream);

    // weight transpose+convert (independent of routing)
    transpose_cvt<<<dim3(HDIM / 32, DIM / 32, NE), 256, 0, stream>>>(gw, WgT, DIM, HDIM);
    transpose_cvt<<<dim3(HDIM / 32, DIM / 32, NE), 256, 0, stream>>>(uw, WuT, DIM, HDIM);
    transpose_cvt<<<dim3(DIM / 32, HDIM / 32, NE), 256, 0, stream>>>(dw, WdT, HDIM, DIM);

    router_kernel<<<T_TOK / 4, 256, 0, stream>>>(x, rw, counts, top_idx, top_w);
    scan_kernel<<<1, 64, 0, stream>>>(counts, offsets, cursors, tl_e, tl_m);
    gather_kernel<<<T_TOK, 256, 0, stream>>>(x, top_idx, top_w, cursors, row_tok, row_w, Abuf);

    gemm1_kernel<<<dim3(HDIM / 128, TSLOTS), 256, 0, stream>>>(Abuf, WgT, WuT, Hbuf,
                                                               offsets, counts, tl_e, tl_m);
    gemm2_kernel<<<dim3(DIM / 128, TSLOTS, 2), 256, 0, stream>>>(Hbuf, WdT, y, offsets, counts,
                                                                 row_tok, row_w, tl_e, tl_m);
}

// Round 8
// 269.605 us; speedup vs baseline: 1.0590x; 1.0340x over previous
//
#include <hip/hip_runtime.h>
#include <hip/hip_bf16.h>
#include <stdint.h>

#define T_TOK 2048
#define DIM   1024
#define HDIM  2048
#define NE    8
#define ROWS_PAD 4224   // 4096 routed rows + 128 pad for tile overrun
#define TSLOTS 40       // max live (expert,mtile) pairs: 32 + 7 = 39

typedef __attribute__((ext_vector_type(8))) short bf16x8;
typedef __attribute__((ext_vector_type(4))) float f32x4;

__device__ __forceinline__ unsigned short f2bf(float f) {
    union { float f; unsigned int u; } v; v.f = f;
    unsigned int r = v.u + 0x7FFF + ((v.u >> 16) & 1);   // round-nearest-even
    return (unsigned short)(r >> 16);
}

__device__ __forceinline__ float bf2f(unsigned short b) {
    union { unsigned int u; float f; } v; v.u = ((unsigned int)b) << 16;
    return v.f;
}

__device__ __forceinline__ void gload16(const void* g, void* l) {
    __builtin_amdgcn_global_load_lds(
        (const __attribute__((address_space(1))) void*)g,
        (__attribute__((address_space(3))) void*)l, 16, 0, 0);
}

// ---------------- transpose + fp32->bf16 convert: in[b][R][C] -> out[b][C][R]
__global__ void transpose_cvt(const float* __restrict__ in, unsigned short* __restrict__ out,
                              int R, int C) {
    __shared__ float tile[32][33];
    int b = blockIdx.z;
    int bx = blockIdx.x, by = blockIdx.y;
    int tx = threadIdx.x & 31, ty = threadIdx.x >> 5;
    const float* ip = in + (size_t)b * R * C;
    unsigned short* op = out + (size_t)b * R * C;
#pragma unroll
    for (int i = 0; i < 4; ++i) {
        int r = by * 32 + ty + i * 8;
        tile[ty + i * 8][tx] = ip[(size_t)r * C + bx * 32 + tx];
    }
    __syncthreads();
#pragma unroll
    for (int i = 0; i < 2; ++i) {
        int oc = i * 16 + (threadIdx.x >> 4);     // col of in = row of out (0..31)
        int orw2 = (threadIdx.x & 15) * 2;        // row of in = col of out, pair
        ushort2 v;
        v.x = f2bf(tile[orw2][oc]);
        v.y = f2bf(tile[orw2 + 1][oc]);
        *(ushort2*)&op[(size_t)(bx * 32 + oc) * R + by * 32 + orw2] = v;
    }
}

// ---------------- router: logits = x @ rw, top-2 softmax, counts
__global__ void router_kernel(const float* __restrict__ x, const float* __restrict__ rw,
                              int* __restrict__ counts, int* __restrict__ top_idx,
                              float* __restrict__ top_w) {
    int wid = (blockIdx.x * blockDim.x + threadIdx.x) >> 6;
    int lane = threadIdx.x & 63;
    if (wid >= T_TOK) return;
    float acc[NE];
#pragma unroll
    for (int e = 0; e < NE; ++e) acc[e] = 0.f;
    const float* xr = x + (size_t)wid * DIM;
    for (int i = lane; i < DIM; i += 64) {
        float xv = xr[i];
        const float* wr = rw + (size_t)i * NE;
#pragma unroll
        for (int e = 0; e < NE; ++e) acc[e] += xv * wr[e];
    }
#pragma unroll
    for (int off = 32; off; off >>= 1) {
#pragma unroll
        for (int e = 0; e < NE; ++e) acc[e] += __shfl_xor(acc[e], off, 64);
    }
    if (lane == 0) {
        float v0 = -1e30f, v1 = -1e30f; int i0 = 0, i1 = 0;
#pragma unroll
        for (int e = 0; e < NE; ++e) {
            float v = acc[e];
            if (v > v0) { v1 = v0; i1 = i0; v0 = v; i0 = e; }
            else if (v > v1) { v1 = v; i1 = e; }
        }
        float e1 = __expf(v1 - v0);
        float s = 1.f + e1;
        top_idx[wid * 2]     = i0;
        top_idx[wid * 2 + 1] = i1;
        top_w[wid * 2]     = 1.f / s;
        top_w[wid * 2 + 1] = e1 / s;
        atomicAdd(&counts[i0], 1);
        atomicAdd(&counts[i1], 1);
    }
}

// ---------------- scan + compact tile list (holes only at the tail)
__global__ void scan_kernel(const int* __restrict__ counts, int* __restrict__ offsets,
                            int* __restrict__ cursors,
                            int* __restrict__ tl_e, int* __restrict__ tl_m) {
    if (threadIdx.x == 0) {
        int run = 0;
        for (int e = 0; e < NE; ++e) { offsets[e] = run; cursors[e] = run; run += counts[e]; }
        int n = 0;
        for (int e = 0; e < NE; ++e) {
            int mt = (counts[e] + 127) >> 7;
            for (int m = 0; m < mt && n < 64; ++m) { tl_e[n] = e; tl_m[n] = m; ++n; }
        }
        for (; n < 64; ++n) tl_e[n] = -1;
    }
}

// ---------------- gather: pack each token's row (bf16) into its 2 experts' segments
__global__ void gather_kernel(const float* __restrict__ x, const int* __restrict__ top_idx,
                              const float* __restrict__ top_w, int* __restrict__ cursors,
                              int* __restrict__ row_tok, float* __restrict__ row_w,
                              unsigned short* __restrict__ Abuf) {
    int t = blockIdx.x;
    __shared__ int pos[2];
    if (threadIdx.x < 2) {
        int k = threadIdx.x;
        int e = top_idx[t * 2 + k];
        int p = atomicAdd(&cursors[e], 1);
        pos[k] = p;
        row_tok[p] = t;
        row_w[p] = top_w[t * 2 + k];
    }
    __syncthreads();
    const float4* xr = (const float4*)(x + (size_t)t * DIM);
    float4 v = xr[threadIdx.x];
    ushort4 b;
    b.x = f2bf(v.x); b.y = f2bf(v.y); b.z = f2bf(v.z); b.w = f2bf(v.w);
    ushort4* A4 = (ushort4*)Abuf;
    A4[(size_t)pos[0] * (DIM / 4) + threadIdx.x] = b;
    A4[(size_t)pos[1] * (DIM / 4) + threadIdx.x] = b;
}

// ---------------- GEMM1: hidden = silu(A @ Wg^T) * (A @ Wu^T), per expert
// BM=128, BN=64; 4 waves = 2(m) x 2(gate|up); 32KB LDS double-buffered;
// silu combine via bf16 LDS exchange in epilogue. Compact tile-list grid.
__global__ __launch_bounds__(256, 4)
void gemm1_kernel(const unsigned short* __restrict__ Abuf,
                  const unsigned short* __restrict__ WgT,
                  const unsigned short* __restrict__ WuT,
                  unsigned short* __restrict__ Hbuf,
                  const int* __restrict__ offsets, const int* __restrict__ counts,
                  const int* __restrict__ tl_e, const int* __restrict__ tl_m) {
    const int slot = blockIdx.y;
    const int e = tl_e[slot];
    if (e < 0) return;
    const int mtile = tl_m[slot];
    const int cnt = counts[e];
    const int n0 = blockIdx.x * 64;
    const int row0 = offsets[e] + mtile * 128;

    __shared__ __align__(16) unsigned char lds_raw[32768];
    unsigned short* AsB = (unsigned short*)lds_raw;            // [2][128*32] = 16KB
    unsigned short* BgB = (unsigned short*)(lds_raw + 16384);  // [2][64*32]  =  8KB
    unsigned short* BuB = (unsigned short*)(lds_raw + 24576);  // [2][64*32]  =  8KB
    unsigned short* ex  = (unsigned short*)lds_raw;            // epilogue [2][64][64] bf16 = 16KB (aliases AsB)

    const int tid = threadIdx.x;
    const int lane = tid & 63;
    const int wave = tid >> 6;
    const int wm = wave >> 1;        // m-half (0,1)
    const int wu = wave & 1;         // 0 = gate, 1 = up

    f32x4 acc[4][4];
#pragma unroll
    for (int i = 0; i < 4; ++i)
#pragma unroll
        for (int j = 0; j < 4; ++j) acc[i][j] = (f32x4){0.f, 0.f, 0.f, 0.f};

    // staging: A = 2 issues (128 rows), Bg = 1 issue (64 rows), Bu = 1 issue
    const int srow = tid >> 2;          // 0..63
    const int sc0 = tid & 3;            // 16B-chunk within 64B row
    const unsigned short* Aab = Abuf + (size_t)row0 * DIM;
    const unsigned short* Bgb = WgT + (size_t)e * HDIM * DIM + (size_t)n0 * DIM;
    const unsigned short* Bub = WuT + (size_t)e * HDIM * DIM + (size_t)n0 * DIM;

    auto stage = [&](int buf, int kt) {
#pragma unroll
        for (int i = 0; i < 2; ++i) {
            int row = i * 64 + srow;
            int csrc = sc0 ^ ((row >> 1) & 3);            // inverse swizzle on source
            gload16(Aab + (size_t)row * DIM + kt + csrc * 8,
                    AsB + buf * 4096 + (i * 256 + tid) * 8);
        }
        int csrcb = sc0 ^ ((srow >> 1) & 3);
        gload16(Bgb + (size_t)srow * DIM + kt + csrcb * 8, BgB + buf * 2048 + tid * 8);
        gload16(Bub + (size_t)srow * DIM + kt + csrcb * 8, BuB + buf * 2048 + tid * 8);
    };

    const int rsel = lane & 15;
    const int csrcf = lane >> 4;        // fragment k-chunk (0..3)

    stage(0, 0);
    int cur = 0;
    for (int kt = 0; kt < DIM; kt += 32) {
        __syncthreads();
        if (kt + 32 < DIM) stage(cur ^ 1, kt + 32);
        const unsigned short* Ac = AsB + cur * 4096;
        const unsigned short* Bc = (wu ? BuB : BgB) + cur * 2048;
        bf16x8 af[4], bb[4];
#pragma unroll
        for (int i = 0; i < 4; ++i) {
            int ra = wm * 64 + i * 16 + rsel;
            af[i] = *(const bf16x8*)&Ac[ra * 32 + (csrcf ^ ((ra >> 1) & 3)) * 8];
            int rb = i * 16 + rsel;
            bb[i] = *(const bf16x8*)&Bc[rb * 32 + (csrcf ^ ((rb >> 1) & 3)) * 8];
        }
#pragma unroll
        for (int i = 0; i < 4; ++i)
#pragma unroll
            for (int j = 0; j < 4; ++j)
                acc[i][j] = __builtin_amdgcn_mfma_f32_16x16x32_bf16(af[i], bb[j], acc[i][j], 0, 0, 0);
        cur ^= 1;
    }

    // ---- epilogue: up-waves export u (bf16) via LDS; gate-waves apply silu(g)*u
    const int c = lane & 15, rbase = (lane >> 4) * 4;
    const int obase = offsets[e];
    __syncthreads();                    // all staging reads done; safe to alias LDS
    if (wu) {
#pragma unroll
        for (int i = 0; i < 4; ++i)
#pragma unroll
            for (int r = 0; r < 4; ++r) {
                int row64 = i * 16 + rbase + r;
#pragma unroll
                for (int j = 0; j < 4; ++j)
                    ex[wm * 4096 + row64 * 64 + j * 16 + c] = f2bf(acc[i][j][r]);
            }
    }
    __syncthreads();
    if (!wu) {
#pragma unroll
        for (int i = 0; i < 4; ++i) {
#pragma unroll
            for (int r = 0; r < 4; ++r) {
                int row64 = i * 16 + rbase + r;
                int lrow = mtile * 128 + wm * 64 + row64;
                if (lrow < cnt) {
                    size_t orow = (size_t)(obase + lrow);
#pragma unroll
                    for (int j = 0; j < 4; ++j) {
                        float g = acc[i][j][r];
                        float u = bf2f(ex[wm * 4096 + row64 * 64 + j * 16 + c]);
                        float h = g * u / (1.f + __expf(-g));
                        Hbuf[orow * HDIM + n0 + j * 16 + c] = f2bf(h);
                    }
                }
            }
        }
    }
}

// ---------------- GEMM2: y[tok] += w * (hidden @ WdT^T)
// 3-buffer depth-2 prefetch, counted vmcnt + raw s_barrier, BK=32, K split x2,
// compact tile-list grid.
__global__ __launch_bounds__(256, 3)
void gemm2_kernel(const unsigned short* __restrict__ Hbuf,
                  const unsigned short* __restrict__ WdT,
                  float* __restrict__ y,
                  const int* __restrict__ offsets, const int* __restrict__ counts,
                  const int* __restrict__ row_tok, const float* __restrict__ row_w,
                  const int* __restrict__ tl_e, const int* __restrict__ tl_m) {
    const int slot = blockIdx.y;
    const int e = tl_e[slot];
    if (e < 0) return;
    const int mtile = tl_m[slot];
    const int kc = blockIdx.z;
    const int cnt = counts[e];
    const int n0 = blockIdx.x * 128;
    const int row0 = offsets[e] + mtile * 128;

    __shared__ unsigned short As[3][128 * 32];   // 24 KB
    __shared__ unsigned short Bs[3][128 * 32];   // 24 KB  (48 KB -> 3 blocks/CU)

    const int tid = threadIdx.x;
    const int lane = tid & 63;
    const int wave = tid >> 6;
    const int wm = wave >> 1, wn = wave & 1;

    f32x4 acc[4][4];
#pragma unroll
    for (int i = 0; i < 4; ++i)
#pragma unroll
        for (int j = 0; j < 4; ++j) acc[i][j] = (f32x4){0.f, 0.f, 0.f, 0.f};

    // staging: 2 issues x 2 arrays = 4 gload16 per thread per stage
    const int srow0 = tid >> 2;
    const int sc0 = tid & 3;
    const unsigned short* Aab = Hbuf + (size_t)row0 * HDIM;
    const unsigned short* Bbb = WdT + (size_t)e * DIM * HDIM + (size_t)n0 * HDIM;

    auto stage = [&](int buf, int kt) {
#pragma unroll
        for (int i = 0; i < 2; ++i) {
            int row = i * 64 + srow0;
            int csrc = sc0 ^ ((row >> 1) & 3);
            size_t go = (size_t)row * HDIM + kt + csrc * 8;
            int lo = (i * 256 + tid) * 8;
            gload16(Aab + go, &As[buf][lo]);
            gload16(Bbb + go, &Bs[buf][lo]);
        }
    };

    const int rsel = lane & 15;
    const int csrcf = lane >> 4;

    const int kbeg = kc * (HDIM / 2);
    const int NS = (HDIM / 2) / 32;     // 32 K-steps

    stage(0, kbeg);
    stage(1, kbeg + 32);
    int cur = 0;
    for (int s = 0; s < NS; ++s) {
        if (s + 1 < NS) { asm volatile("s_waitcnt vmcnt(4)" ::: "memory"); }
        else            { asm volatile("s_waitcnt vmcnt(0)" ::: "memory"); }
        __builtin_amdgcn_s_barrier();
        if (s + 2 < NS) {
            int pb = cur + 2; if (pb >= 3) pb -= 3;
            stage(pb, kbeg + (s + 2) * 32);
        }
        const unsigned short* Ac = As[cur];
        const unsigned short* Bc = Bs[cur];
        bf16x8 af[4], bf[4];
#pragma unroll
        for (int i = 0; i < 4; ++i) {
            int ra = wm * 64 + i * 16 + rsel;
            af[i] = *(const bf16x8*)&Ac[ra * 32 + (csrcf ^ ((ra >> 1) & 3)) * 8];
            int rb = wn * 64 + i * 16 + rsel;
            bf[i] = *(const bf16x8*)&Bc[rb * 32 + (csrcf ^ ((rb >> 1) & 3)) * 8];
        }
#pragma unroll
        for (int i = 0; i < 4; ++i)
#pragma unroll
            for (int j = 0; j < 4; ++j)
                acc[i][j] = __builtin_amdgcn_mfma_f32_16x16x32_bf16(af[i], bf[j], acc[i][j], 0, 0, 0);
        ++cur; if (cur == 3) cur = 0;
    }

    const int c = lane & 15, rbase = (lane >> 4) * 4;
    const int obase = offsets[e];
#pragma unroll
    for (int i = 0; i < 4; ++i) {
#pragma unroll
        for (int r = 0; r < 4; ++r) {
            int lrow = mtile * 128 + wm * 64 + i * 16 + rbase + r;
            if (lrow < cnt) {
                int grow = obase + lrow;
                int tok = row_tok[grow];
                float w = row_w[grow];
#pragma unroll
                for (int j = 0; j < 4; ++j) {
                    atomicAdd(&y[(size_t)tok * DIM + n0 + wn * 64 + j * 16 + c], w * acc[i][j][r]);
                }
            }
        }
    }
}

extern "C" void kernel_launch(void* const* d_in, const int* in_sizes, int n_in,
                              void* d_out, int out_size, void* d_ws, size_t ws_size,
                              hipStream_t stream) {
    const float* x  = (const float*)d_in[0];
    const float* rw = (const float*)d_in[1];
    const float* gw = (const float*)d_in[2];
    const float* uw = (const float*)d_in[3];
    const float* dw = (const float*)d_in[4];
    float* y = (float*)d_out;

    char* ws = (char*)d_ws;
    int*   counts  = (int*)(ws + 0);
    int*   cursors = (int*)(ws + 32);
    int*   offsets = (int*)(ws + 64);
    int*   top_idx = (int*)(ws + 128);
    float* top_w   = (float*)(ws + 128 + 16384);
    int*   row_tok = (int*)(ws + 128 + 32768);
    float* row_w   = (float*)(ws + 128 + 32768 + 16896);
    int*   tl_e    = (int*)(ws + 128 + 32768 + 2 * 16896);
    int*   tl_m    = (int*)(ws + 128 + 32768 + 2 * 16896 + 256);
    size_t off = 128 + 32768 + 2 * 16896 + 512;
    off = (off + 255) & ~(size_t)255;
    unsigned short* Abuf = (unsigned short*)(ws + off); off += (size_t)ROWS_PAD * DIM * 2;
    unsigned short* Hbuf = (unsigned short*)(ws + off); off += (size_t)ROWS_PAD * HDIM * 2;
    unsigned short* WgT  = (unsigned short*)(ws + off); off += (size_t)NE * DIM * HDIM * 2;
    unsigned short* WuT  = (unsigned short*)(ws + off); off += (size_t)NE * DIM * HDIM * 2;
    unsigned short* WdT  = (unsigned short*)(ws + off); off += (size_t)NE * DIM * HDIM * 2;
    if (ws_size < off) return;  // workspace too small: fail loudly (zero output)

    hipMemsetAsync(counts, 0, 32, stream);
    hipMemsetAsync(d_out, 0, (size_t)out_size * 4, stream);

    // weight transpose+convert (independent of routing)
    transpose_cvt<<<dim3(HDIM / 32, DIM / 32, NE), 256, 0, stream>>>(gw, WgT, DIM, HDIM);
    transpose_cvt<<<dim3(HDIM / 32, DIM / 32, NE), 256, 0, stream>>>(uw, WuT, DIM, HDIM);
    transpose_cvt<<<dim3(DIM / 32, HDIM / 32, NE), 256, 0, stream>>>(dw, WdT, HDIM, DIM);

    router_kernel<<<T_TOK / 4, 256, 0, stream>>>(x, rw, counts, top_idx, top_w);
    scan_kernel<<<1, 64, 0, stream>>>(counts, offsets, cursors, tl_e, tl_m);
    gather_kernel<<<T_TOK, 256, 0, stream>>>(x, top_idx, top_w, cursors, row_tok, row_w, Abuf);

    gemm1_kernel<<<dim3(HDIM / 64, TSLOTS), 256, 0, stream>>>(Abuf, WgT, WuT, Hbuf,
                                                              offsets, counts, tl_e, tl_m);
    gemm2_kernel<<<dim3(DIM / 128, TSLOTS, 2), 256, 0, stream>>>(Hbuf, WdT, y, offsets, counts,
                                                                 row_tok, row_w, tl_e, tl_m);
}

// Round 10
// 262.699 us; speedup vs baseline: 1.0868x; 1.0263x over previous
//
#include <hip/hip_runtime.h>
#include <hip/hip_bf16.h>
#include <stdint.h>

#define T_TOK 2048
#define DIM   1024
#define HDIM  2048
#define NE    8
#define ROWS_PAD 4224   // 4096 routed rows + 128 pad for tile overrun
#define TSLOTS 40       // max live (expert,mtile) pairs: 32 + 7 = 39

typedef __attribute__((ext_vector_type(8))) short bf16x8;
typedef __attribute__((ext_vector_type(4))) float f32x4;

__device__ __forceinline__ unsigned short f2bf(float f) {
    union { float f; unsigned int u; } v; v.f = f;
    unsigned int r = v.u + 0x7FFF + ((v.u >> 16) & 1);   // round-nearest-even
    return (unsigned short)(r >> 16);
}

__device__ __forceinline__ float bf2f(unsigned short b) {
    union { unsigned int u; float f; } v; v.u = ((unsigned int)b) << 16;
    return v.f;
}

__device__ __forceinline__ void gload16(const void* g, void* l) {
    __builtin_amdgcn_global_load_lds(
        (const __attribute__((address_space(1))) void*)g,
        (__attribute__((address_space(3))) void*)l, 16, 0, 0);
}

// ---------------- prep: fused {gw,uw,dw transpose+cvt} + router in one launch
// blocks [0, 49152): transpose tiles; [49152, 49664): router (4 tokens/block)
#define NTT (3 * 16384)
__global__ void prep_kernel(const float* __restrict__ gw, const float* __restrict__ uw,
                            const float* __restrict__ dw,
                            unsigned short* __restrict__ WgT, unsigned short* __restrict__ WuT,
                            unsigned short* __restrict__ WdT,
                            const float* __restrict__ x, const float* __restrict__ rw,
                            int* __restrict__ counts, int* __restrict__ top_idx,
                            float* __restrict__ top_w) {
    __shared__ float tile[32][33];
    const int b = blockIdx.x;
    if (b < NTT) {
        const int m = b >> 14;          // 0=gw, 1=uw, 2=dw
        const int t = b & 16383;
        const int e = t >> 11;
        const int rem = t & 2047;
        const float* in; unsigned short* out; int R, C, by, bx;
        if (m == 0)      { in = gw; out = WgT; R = DIM;  C = HDIM; by = rem >> 6; bx = rem & 63; }
        else if (m == 1) { in = uw; out = WuT; R = DIM;  C = HDIM; by = rem >> 6; bx = rem & 63; }
        else             { in = dw; out = WdT; R = HDIM; C = DIM;  by = rem >> 5; bx = rem & 31; }
        const float* ip = in + (size_t)e * R * C;
        unsigned short* op = out + (size_t)e * R * C;
        const int tx = threadIdx.x & 31, ty = threadIdx.x >> 5;
#pragma unroll
        for (int i = 0; i < 4; ++i)
            tile[ty + i * 8][tx] = ip[(size_t)(by * 32 + ty + i * 8) * C + bx * 32 + tx];
        __syncthreads();
#pragma unroll
        for (int i = 0; i < 2; ++i) {
            int oc = i * 16 + (threadIdx.x >> 4);
            int orw2 = (threadIdx.x & 15) * 2;
            ushort2 v;
            v.x = f2bf(tile[orw2][oc]);
            v.y = f2bf(tile[orw2 + 1][oc]);
            *(ushort2*)&op[(size_t)(bx * 32 + oc) * R + by * 32 + orw2] = v;
        }
    } else {
        const int wid = (b - NTT) * 4 + (threadIdx.x >> 6);
        const int lane = threadIdx.x & 63;
        if (wid >= T_TOK) return;
        float acc[NE];
#pragma unroll
        for (int e = 0; e < NE; ++e) acc[e] = 0.f;
        const float* xr = x + (size_t)wid * DIM;
        for (int i = lane; i < DIM; i += 64) {
            float xv = xr[i];
            const float* wr = rw + (size_t)i * NE;
#pragma unroll
            for (int e = 0; e < NE; ++e) acc[e] += xv * wr[e];
        }
#pragma unroll
        for (int off = 32; off; off >>= 1) {
#pragma unroll
            for (int e = 0; e < NE; ++e) acc[e] += __shfl_xor(acc[e], off, 64);
        }
        if (lane == 0) {
            float v0 = -1e30f, v1 = -1e30f; int i0 = 0, i1 = 0;
#pragma unroll
            for (int e = 0; e < NE; ++e) {
                float v = acc[e];
                if (v > v0) { v1 = v0; i1 = i0; v0 = v; i0 = e; }
                else if (v > v1) { v1 = v; i1 = e; }
            }
            float e1 = __expf(v1 - v0);
            float s = 1.f + e1;
            top_idx[wid * 2]     = i0;
            top_idx[wid * 2 + 1] = i1;
            top_w[wid * 2]     = 1.f / s;
            top_w[wid * 2 + 1] = e1 / s;
            atomicAdd(&counts[i0], 1);
            atomicAdd(&counts[i1], 1);
        }
    }
}

// ---------------- scan + compact tile list (holes only at the tail)
__global__ void scan_kernel(const int* __restrict__ counts, int* __restrict__ offsets,
                            int* __restrict__ cursors,
                            int* __restrict__ tl_e, int* __restrict__ tl_m) {
    if (threadIdx.x == 0) {
        int run = 0;
        for (int e = 0; e < NE; ++e) { offsets[e] = run; cursors[e] = run; run += counts[e]; }
        int n = 0;
        for (int e = 0; e < NE; ++e) {
            int mt = (counts[e] + 127) >> 7;
            for (int m = 0; m < mt && n < 64; ++m) { tl_e[n] = e; tl_m[n] = m; ++n; }
        }
        for (; n < 64; ++n) tl_e[n] = -1;
    }
}

// ---------------- gather: pack each token's row (bf16) into its 2 experts' segments
__global__ void gather_kernel(const float* __restrict__ x, const int* __restrict__ top_idx,
                              const float* __restrict__ top_w, int* __restrict__ cursors,
                              int* __restrict__ row_tok, float* __restrict__ row_w,
                              unsigned short* __restrict__ Abuf) {
    int t = blockIdx.x;
    __shared__ int pos[2];
    if (threadIdx.x < 2) {
        int k = threadIdx.x;
        int e = top_idx[t * 2 + k];
        int p = atomicAdd(&cursors[e], 1);
        pos[k] = p;
        row_tok[p] = t;
        row_w[p] = top_w[t * 2 + k];
    }
    __syncthreads();
    const float4* xr = (const float4*)(x + (size_t)t * DIM);
    float4 v = xr[threadIdx.x];
    ushort4 b;
    b.x = f2bf(v.x); b.y = f2bf(v.y); b.z = f2bf(v.z); b.w = f2bf(v.w);
    ushort4* A4 = (ushort4*)Abuf;
    A4[(size_t)pos[0] * (DIM / 4) + threadIdx.x] = b;
    A4[(size_t)pos[1] * (DIM / 4) + threadIdx.x] = b;
}

// ---------------- GEMM1: hidden = silu(A @ Wg^T) * (A @ Wu^T), per expert
// BM=128, BN=64, BK=64 (16 steps); 4 waves = 2(m) x 2(gate|up);
// 64KB LDS double-buffered; silu combine via bf16 LDS exchange.
__global__ __launch_bounds__(256, 2)
void gemm1_kernel(const unsigned short* __restrict__ Abuf,
                  const unsigned short* __restrict__ WgT,
                  const unsigned short* __restrict__ WuT,
                  unsigned short* __restrict__ Hbuf,
                  const int* __restrict__ offsets, const int* __restrict__ counts,
                  const int* __restrict__ tl_e, const int* __restrict__ tl_m) {
    const int slot = blockIdx.y;
    const int e = tl_e[slot];
    if (e < 0) return;
    const int mtile = tl_m[slot];
    const int cnt = counts[e];
    const int n0 = blockIdx.x * 64;
    const int row0 = offsets[e] + mtile * 128;

    __shared__ __align__(16) unsigned char lds_raw[65536];
    unsigned short* AsB = (unsigned short*)lds_raw;            // [2][128*64] = 32KB
    unsigned short* BgB = (unsigned short*)(lds_raw + 32768);  // [2][64*64]  = 16KB
    unsigned short* BuB = (unsigned short*)(lds_raw + 49152);  // [2][64*64]  = 16KB
    unsigned short* ex  = (unsigned short*)lds_raw;            // epilogue [2][64][64] bf16 = 16KB (aliases AsB)

    const int tid = threadIdx.x;
    const int lane = tid & 63;
    const int wave = tid >> 6;
    const int wm = wave >> 1;        // m-half (0,1)
    const int wu = wave & 1;         // 0 = gate, 1 = up

    f32x4 acc[4][4];
#pragma unroll
    for (int i = 0; i < 4; ++i)
#pragma unroll
        for (int j = 0; j < 4; ++j) acc[i][j] = (f32x4){0.f, 0.f, 0.f, 0.f};

    // staging: rows of 64 shorts = 8 x 16B chunks; swizzle chunk ^= row&7
    const int srow = tid >> 3;          // 0..31
    const int sc0 = tid & 7;            // 16B-chunk within 128B row
    const unsigned short* Aab = Abuf + (size_t)row0 * DIM;
    const unsigned short* Bgb = WgT + (size_t)e * HDIM * DIM + (size_t)n0 * DIM;
    const unsigned short* Bub = WuT + (size_t)e * HDIM * DIM + (size_t)n0 * DIM;

    auto stage = [&](int buf, int kt) {
#pragma unroll
        for (int i = 0; i < 4; ++i) {                          // A: 128 rows
            int row = i * 32 + srow;
            int csrc = sc0 ^ (row & 7);
            gload16(Aab + (size_t)row * DIM + kt + csrc * 8,
                    AsB + buf * 8192 + (i * 256 + tid) * 8);
        }
#pragma unroll
        for (int i = 0; i < 2; ++i) {                          // Bg, Bu: 64 rows each
            int row = i * 32 + srow;
            int csrc = sc0 ^ (row & 7);
            size_t go = (size_t)row * DIM + kt + csrc * 8;
            gload16(Bgb + go, BgB + buf * 4096 + (i * 256 + tid) * 8);
            gload16(Bub + go, BuB + buf * 4096 + (i * 256 + tid) * 8);
        }
    };

    const int rsel = lane & 15;
    const int csrcf = lane >> 4;        // fragment k-chunk (0..3)

    stage(0, 0);
    int cur = 0;
    for (int kt = 0; kt < DIM; kt += 64) {
        __syncthreads();
        if (kt + 64 < DIM) stage(cur ^ 1, kt + 64);
        const unsigned short* Ac = AsB + cur * 8192;
        const unsigned short* Bc = (wu ? BuB : BgB) + cur * 4096;
#pragma unroll
        for (int kk = 0; kk < 2; ++kk) {
            bf16x8 af[4], bb[4];
#pragma unroll
            for (int i = 0; i < 4; ++i) {
                int ra = wm * 64 + i * 16 + rsel;
                af[i] = *(const bf16x8*)&Ac[ra * 64 + ((kk * 4 + csrcf) ^ (ra & 7)) * 8];
                int rb = i * 16 + rsel;
                bb[i] = *(const bf16x8*)&Bc[rb * 64 + ((kk * 4 + csrcf) ^ (rb & 7)) * 8];
            }
#pragma unroll
            for (int i = 0; i < 4; ++i)
#pragma unroll
                for (int j = 0; j < 4; ++j)
                    acc[i][j] = __builtin_amdgcn_mfma_f32_16x16x32_bf16(af[i], bb[j], acc[i][j], 0, 0, 0);
        }
        cur ^= 1;
    }

    // ---- epilogue: up-waves export u (bf16) via LDS; gate-waves apply silu(g)*u
    const int c = lane & 15, rbase = (lane >> 4) * 4;
    const int obase = offsets[e];
    __syncthreads();                    // all staging reads done; safe to alias LDS
    if (wu) {
#pragma unroll
        for (int i = 0; i < 4; ++i)
#pragma unroll
            for (int r = 0; r < 4; ++r) {
                int row64 = i * 16 + rbase + r;
#pragma unroll
                for (int j = 0; j < 4; ++j)
                    ex[wm * 4096 + row64 * 64 + j * 16 + c] = f2bf(acc[i][j][r]);
            }
    }
    __syncthreads();
    if (!wu) {
#pragma unroll
        for (int i = 0; i < 4; ++i) {
#pragma unroll
            for (int r = 0; r < 4; ++r) {
                int row64 = i * 16 + rbase + r;
                int lrow = mtile * 128 + wm * 64 + row64;
                if (lrow < cnt) {
                    size_t orow = (size_t)(obase + lrow);
#pragma unroll
                    for (int j = 0; j < 4; ++j) {
                        float g = acc[i][j][r];
                        float u = bf2f(ex[wm * 4096 + row64 * 64 + j * 16 + c]);
                        float h = g * u / (1.f + __expf(-g));
                        Hbuf[orow * HDIM + n0 + j * 16 + c] = f2bf(h);
                    }
                }
            }
        }
    }
}

// ---------------- GEMM2: y[tok] += w * (hidden @ WdT^T)
// 2-phase double-buffered, BK=64, XOR-swizzled LDS (c ^= row&7), K split x2,
// compact tile-list grid.  (R5-proven inner loop.)
__global__ __launch_bounds__(256, 2)
void gemm2_kernel(const unsigned short* __restrict__ Hbuf,
                  const unsigned short* __restrict__ WdT,
                  float* __restrict__ y,
                  const int* __restrict__ offsets, const int* __restrict__ counts,
                  const int* __restrict__ row_tok, const float* __restrict__ row_w,
                  const int* __restrict__ tl_e, const int* __restrict__ tl_m) {
    const int slot = blockIdx.y;
    const int e = tl_e[slot];
    if (e < 0) return;
    const int mtile = tl_m[slot];
    const int kc = blockIdx.z;
    const int cnt = counts[e];
    const int n0 = blockIdx.x * 128;
    const int row0 = offsets[e] + mtile * 128;

    __shared__ unsigned short As[2][128 * 64];   // 32 KB
    __shared__ unsigned short Bs[2][128 * 64];   // 32 KB

    const int tid = threadIdx.x;
    const int lane = tid & 63;
    const int wave = tid >> 6;
    const int wm = wave >> 1, wn = wave & 1;

    f32x4 acc[4][4];
#pragma unroll
    for (int i = 0; i < 4; ++i)
#pragma unroll
        for (int j = 0; j < 4; ++j) acc[i][j] = (f32x4){0.f, 0.f, 0.f, 0.f};

    const int srow0 = tid >> 3;          // row within 32-row quarter (+i*32)
    const int sc0 = tid & 7;             // LDS 16B-chunk within 128B row
    const unsigned short* Aab = Hbuf + (size_t)row0 * HDIM;
    const unsigned short* Bbb = WdT + (size_t)e * DIM * HDIM + (size_t)n0 * HDIM;

    auto stage = [&](int buf, int kt) {
#pragma unroll
        for (int i = 0; i < 4; ++i) {
            int row = i * 32 + srow0;
            int csrc = sc0 ^ (row & 7);
            size_t go = (size_t)row * HDIM + kt + csrc * 8;
            int lo = (i * 256 + tid) * 8;
            gload16(Aab + go, &As[buf][lo]);
            gload16(Bbb + go, &Bs[buf][lo]);
        }
    };

    const int rsel = lane & 15;
    const int csrcf = lane >> 4;

    const int kbeg = kc * (HDIM / 2);
    const int kend = kbeg + (HDIM / 2);

    stage(0, kbeg);
    int cur = 0;
    for (int kt = kbeg; kt < kend; kt += 64) {
        __syncthreads();
        if (kt + 64 < kend) stage(cur ^ 1, kt + 64);
        const unsigned short* Ac = As[cur];
        const unsigned short* Bc = Bs[cur];
#pragma unroll
        for (int kk = 0; kk < 2; ++kk) {
            bf16x8 af[4], bf[4];
#pragma unroll
            for (int i = 0; i < 4; ++i) {
                int ra = wm * 64 + i * 16 + rsel;
                af[i] = *(const bf16x8*)&Ac[ra * 64 + ((kk * 4 + csrcf) ^ (ra & 7)) * 8];
                int rb = wn * 64 + i * 16 + rsel;
                bf[i] = *(const bf16x8*)&Bc[rb * 64 + ((kk * 4 + csrcf) ^ (rb & 7)) * 8];
            }
#pragma unroll
            for (int i = 0; i < 4; ++i)
#pragma unroll
                for (int j = 0; j < 4; ++j)
                    acc[i][j] = __builtin_amdgcn_mfma_f32_16x16x32_bf16(af[i], bf[j], acc[i][j], 0, 0, 0);
        }
        cur ^= 1;
    }

    const int c = lane & 15, rbase = (lane >> 4) * 4;
    const int obase = offsets[e];
#pragma unroll
    for (int i = 0; i < 4; ++i) {
#pragma unroll
        for (int r = 0; r < 4; ++r) {
            int lrow = mtile * 128 + wm * 64 + i * 16 + rbase + r;
            if (lrow < cnt) {
                int grow = obase + lrow;
                int tok = row_tok[grow];
                float w = row_w[grow];
#pragma unroll
                for (int j = 0; j < 4; ++j) {
                    atomicAdd(&y[(size_t)tok * DIM + n0 + wn * 64 + j * 16 + c], w * acc[i][j][r]);
                }
            }
        }
    }
}

extern "C" void kernel_launch(void* const* d_in, const int* in_sizes, int n_in,
                              void* d_out, int out_size, void* d_ws, size_t ws_size,
                              hipStream_t stream) {
    const float* x  = (const float*)d_in[0];
    const float* rw = (const float*)d_in[1];
    const float* gw = (const float*)d_in[2];
    const float* uw = (const float*)d_in[3];
    const float* dw = (const float*)d_in[4];
    float* y = (float*)d_out;

    char* ws = (char*)d_ws;
    int*   counts  = (int*)(ws + 0);
    int*   cursors = (int*)(ws + 32);
    int*   offsets = (int*)(ws + 64);
    int*   top_idx = (int*)(ws + 128);
    float* top_w   = (float*)(ws + 128 + 16384);
    int*   row_tok = (int*)(ws + 128 + 32768);
    float* row_w   = (float*)(ws + 128 + 32768 + 16896);
    int*   tl_e    = (int*)(ws + 128 + 32768 + 2 * 16896);
    int*   tl_m    = (int*)(ws + 128 + 32768 + 2 * 16896 + 256);
    size_t off = 128 + 32768 + 2 * 16896 + 512;
    off = (off + 255) & ~(size_t)255;
    unsigned short* Abuf = (unsigned short*)(ws + off); off += (size_t)ROWS_PAD * DIM * 2;
    unsigned short* Hbuf = (unsigned short*)(ws + off); off += (size_t)ROWS_PAD * HDIM * 2;
    unsigned short* WgT  = (unsigned short*)(ws + off); off += (size_t)NE * DIM * HDIM * 2;
    unsigned short* WuT  = (unsigned short*)(ws + off); off += (size_t)NE * DIM * HDIM * 2;
    unsigned short* WdT  = (unsigned short*)(ws + off); off += (size_t)NE * DIM * HDIM * 2;
    if (ws_size < off) return;  // workspace too small: fail loudly (zero output)

    hipMemsetAsync(counts, 0, 32, stream);
    hipMemsetAsync(d_out, 0, (size_t)out_size * 4, stream);

    prep_kernel<<<NTT + T_TOK / 4, 256, 0, stream>>>(gw, uw, dw, WgT, WuT, WdT,
                                                     x, rw, counts, top_idx, top_w);
    scan_kernel<<<1, 64, 0, stream>>>(counts, offsets, cursors, tl_e, tl_m);
    gather_kernel<<<T_TOK, 256, 0, stream>>>(x, top_idx, top_w, cursors, row_tok, row_w, Abuf);

    gemm1_kernel<<<dim3(HDIM / 64, TSLOTS), 256, 0, stream>>>(Abuf, WgT, WuT, Hbuf,
                                                              offsets, counts, tl_e, tl_m);
    gemm2_kernel<<<dim3(DIM / 128, TSLOTS, 2), 256, 0, stream>>>(Hbuf, WdT, y, offsets, counts,
                                                                 row_tok, row_w, tl_e, tl_m);
}

// Round 11
// 257.317 us; speedup vs baseline: 1.1096x; 1.0209x over previous
//
#include <hip/hip_runtime.h>
#include <hip/hip_bf16.h>
#include <stdint.h>

#define T_TOK 2048
#define DIM   1024
#define HDIM  2048
#define NE    8
#define ROWS_PAD 4224   // 4096 routed rows + 128 pad for tile overrun
#define TSLOTS 40       // max live (expert,mtile) pairs: 32 + 7 = 39

typedef __attribute__((ext_vector_type(8))) short bf16x8;
typedef __attribute__((ext_vector_type(8))) unsigned short u16x8;
typedef __attribute__((ext_vector_type(4))) float f32x4;

__device__ __forceinline__ unsigned short f2bf(float f) {
    union { float f; unsigned int u; } v; v.f = f;
    unsigned int r = v.u + 0x7FFF + ((v.u >> 16) & 1);   // round-nearest-even
    return (unsigned short)(r >> 16);
}

__device__ __forceinline__ float bf2f(unsigned short b) {
    union { unsigned int u; float f; } v; v.u = ((unsigned int)b) << 16;
    return v.f;
}

__device__ __forceinline__ void gload16(const void* g, void* l) {
    __builtin_amdgcn_global_load_lds(
        (const __attribute__((address_space(1))) void*)g,
        (__attribute__((address_space(3))) void*)l, 16, 0, 0);
}

// ---------------- prep: fused {gw,uw,dw 64x64-tile transpose+cvt} + router
// blocks [0, 12288): transpose tiles (4096 per matrix); [12288, 12800): router
#define NTT 12288
__global__ void prep_kernel(const float* __restrict__ gw, const float* __restrict__ uw,
                            const float* __restrict__ dw,
                            unsigned short* __restrict__ WgT, unsigned short* __restrict__ WuT,
                            unsigned short* __restrict__ WdT,
                            const float* __restrict__ x, const float* __restrict__ rw,
                            int* __restrict__ counts, int* __restrict__ top_idx,
                            float* __restrict__ top_w) {
    __shared__ __align__(16) unsigned short lt[64 * 66];   // 8448 B
    const int b = blockIdx.x;
    if (b < NTT) {
        const int m = b >> 12;          // 0=gw, 1=uw, 2=dw (4096 tiles each)
        const int t = b & 4095;
        const int e = t >> 9;           // 512 tiles per expert
        const int rem = t & 511;
        const float* in; unsigned short* out; int R, C, by, bx;
        if (m == 0)      { in = gw; out = WgT; R = DIM;  C = HDIM; by = rem >> 5; bx = rem & 31; }
        else if (m == 1) { in = uw; out = WuT; R = DIM;  C = HDIM; by = rem >> 5; bx = rem & 31; }
        else             { in = dw; out = WdT; R = HDIM; C = DIM;  by = rem >> 4; bx = rem & 15; }
        const float* ip = in + (size_t)e * R * C + (size_t)(by * 64) * C + bx * 64;
        unsigned short* op = out + (size_t)e * R * C + (size_t)(bx * 64) * R + by * 64;
        const int r = threadIdx.x >> 2, g = threadIdx.x & 3;
        // phase 1: vectorized fp32 read, cvt, linear LDS write [64][66]
#pragma unroll
        for (int i = 0; i < 4; ++i) {
            int s = g + 4 * i;                       // float4 slot 0..15
            float4 v = *(const float4*)&ip[(size_t)r * C + s * 4];
            ushort4 h;
            h.x = f2bf(v.x); h.y = f2bf(v.y); h.z = f2bf(v.z); h.w = f2bf(v.w);
            *(ushort4*)&lt[r * 66 + s * 4] = h;
        }
        __syncthreads();
        // phase 2: transposed scalar LDS reads (broadcast pairs), 16B global stores
        const int oc = threadIdx.x >> 2;             // out row (= original col)
#pragma unroll
        for (int i = 0; i < 2; ++i) {
            int s = g + 4 * i;                       // 16B slot within out row
            u16x8 h;
#pragma unroll
            for (int k = 0; k < 8; ++k)
                h[k] = lt[(s * 8 + k) * 66 + oc];
            *(u16x8*)&op[(size_t)oc * R + s * 8] = h;
        }
    } else {
        const int wid = (b - NTT) * 4 + (threadIdx.x >> 6);
        const int lane = threadIdx.x & 63;
        if (wid >= T_TOK) return;
        float acc[NE];
#pragma unroll
        for (int e = 0; e < NE; ++e) acc[e] = 0.f;
        const float* xr = x + (size_t)wid * DIM;
        for (int i = lane; i < DIM; i += 64) {
            float xv = xr[i];
            const float* wr = rw + (size_t)i * NE;
#pragma unroll
            for (int e = 0; e < NE; ++e) acc[e] += xv * wr[e];
        }
#pragma unroll
        for (int off = 32; off; off >>= 1) {
#pragma unroll
            for (int e = 0; e < NE; ++e) acc[e] += __shfl_xor(acc[e], off, 64);
        }
        if (lane == 0) {
            float v0 = -1e30f, v1 = -1e30f; int i0 = 0, i1 = 0;
#pragma unroll
            for (int e = 0; e < NE; ++e) {
                float v = acc[e];
                if (v > v0) { v1 = v0; i1 = i0; v0 = v; i0 = e; }
                else if (v > v1) { v1 = v; i1 = e; }
            }
            float e1 = __expf(v1 - v0);
            float s = 1.f + e1;
            top_idx[wid * 2]     = i0;
            top_idx[wid * 2 + 1] = i1;
            top_w[wid * 2]     = 1.f / s;
            top_w[wid * 2 + 1] = e1 / s;
            atomicAdd(&counts[i0], 1);
            atomicAdd(&counts[i1], 1);
        }
    }
}

// ---------------- scan + compact tile list (holes only at the tail)
__global__ void scan_kernel(const int* __restrict__ counts, int* __restrict__ offsets,
                            int* __restrict__ cursors,
                            int* __restrict__ tl_e, int* __restrict__ tl_m) {
    if (threadIdx.x == 0) {
        int run = 0;
        for (int e = 0; e < NE; ++e) { offsets[e] = run; cursors[e] = run; run += counts[e]; }
        int n = 0;
        for (int e = 0; e < NE; ++e) {
            int mt = (counts[e] + 127) >> 7;
            for (int m = 0; m < mt && n < 64; ++m) { tl_e[n] = e; tl_m[n] = m; ++n; }
        }
        for (; n < 64; ++n) tl_e[n] = -1;
    }
}

// ---------------- gather: pack each token's row (bf16) into its 2 experts' segments
__global__ void gather_kernel(const float* __restrict__ x, const int* __restrict__ top_idx,
                              const float* __restrict__ top_w, int* __restrict__ cursors,
                              int* __restrict__ row_tok, float* __restrict__ row_w,
                              unsigned short* __restrict__ Abuf) {
    int t = blockIdx.x;
    __shared__ int pos[2];
    if (threadIdx.x < 2) {
        int k = threadIdx.x;
        int e = top_idx[t * 2 + k];
        int p = atomicAdd(&cursors[e], 1);
        pos[k] = p;
        row_tok[p] = t;
        row_w[p] = top_w[t * 2 + k];
    }
    __syncthreads();
    const float4* xr = (const float4*)(x + (size_t)t * DIM);
    float4 v = xr[threadIdx.x];
    ushort4 b;
    b.x = f2bf(v.x); b.y = f2bf(v.y); b.z = f2bf(v.z); b.w = f2bf(v.w);
    ushort4* A4 = (ushort4*)Abuf;
    A4[(size_t)pos[0] * (DIM / 4) + threadIdx.x] = b;
    A4[(size_t)pos[1] * (DIM / 4) + threadIdx.x] = b;
}

// ---------------- GEMM1: hidden = silu(A @ Wg^T) * (A @ Wu^T), per expert
// BM=128, BN=64, BK=64 (16 steps); 4 waves = 2(m) x 2(gate|up);
// 64KB LDS double-buffered; silu combine via bf16 LDS exchange.
__global__ __launch_bounds__(256, 2)
void gemm1_kernel(const unsigned short* __restrict__ Abuf,
                  const unsigned short* __restrict__ WgT,
                  const unsigned short* __restrict__ WuT,
                  unsigned short* __restrict__ Hbuf,
                  const int* __restrict__ offsets, const int* __restrict__ counts,
                  const int* __restrict__ tl_e, const int* __restrict__ tl_m) {
    const int slot = blockIdx.y;
    const int e = tl_e[slot];
    if (e < 0) return;
    const int mtile = tl_m[slot];
    const int cnt = counts[e];
    const int n0 = blockIdx.x * 64;
    const int row0 = offsets[e] + mtile * 128;

    __shared__ __align__(16) unsigned char lds_raw[65536];
    unsigned short* AsB = (unsigned short*)lds_raw;            // [2][128*64] = 32KB
    unsigned short* BgB = (unsigned short*)(lds_raw + 32768);  // [2][64*64]  = 16KB
    unsigned short* BuB = (unsigned short*)(lds_raw + 49152);  // [2][64*64]  = 16KB
    unsigned short* ex  = (unsigned short*)lds_raw;            // epilogue [2][64][64] bf16 = 16KB (aliases AsB)

    const int tid = threadIdx.x;
    const int lane = tid & 63;
    const int wave = tid >> 6;
    const int wm = wave >> 1;        // m-half (0,1)
    const int wu = wave & 1;         // 0 = gate, 1 = up

    f32x4 acc[4][4];
#pragma unroll
    for (int i = 0; i < 4; ++i)
#pragma unroll
        for (int j = 0; j < 4; ++j) acc[i][j] = (f32x4){0.f, 0.f, 0.f, 0.f};

    // staging: rows of 64 shorts = 8 x 16B chunks; swizzle chunk ^= row&7
    const int srow = tid >> 3;          // 0..31
    const int sc0 = tid & 7;            // 16B-chunk within 128B row
    const unsigned short* Aab = Abuf + (size_t)row0 * DIM;
    const unsigned short* Bgb = WgT + (size_t)e * HDIM * DIM + (size_t)n0 * DIM;
    const unsigned short* Bub = WuT + (size_t)e * HDIM * DIM + (size_t)n0 * DIM;

    auto stage = [&](int buf, int kt) {
#pragma unroll
        for (int i = 0; i < 4; ++i) {                          // A: 128 rows
            int row = i * 32 + srow;
            int csrc = sc0 ^ (row & 7);
            gload16(Aab + (size_t)row * DIM + kt + csrc * 8,
                    AsB + buf * 8192 + (i * 256 + tid) * 8);
        }
#pragma unroll
        for (int i = 0; i < 2; ++i) {                          // Bg, Bu: 64 rows each
            int row = i * 32 + srow;
            int csrc = sc0 ^ (row & 7);
            size_t go = (size_t)row * DIM + kt + csrc * 8;
            gload16(Bgb + go, BgB + buf * 4096 + (i * 256 + tid) * 8);
            gload16(Bub + go, BuB + buf * 4096 + (i * 256 + tid) * 8);
        }
    };

    const int rsel = lane & 15;
    const int csrcf = lane >> 4;        // fragment k-chunk (0..3)

    stage(0, 0);
    int cur = 0;
    for (int kt = 0; kt < DIM; kt += 64) {
        __syncthreads();
        if (kt + 64 < DIM) stage(cur ^ 1, kt + 64);
        const unsigned short* Ac = AsB + cur * 8192;
        const unsigned short* Bc = (wu ? BuB : BgB) + cur * 4096;
#pragma unroll
        for (int kk = 0; kk < 2; ++kk) {
            bf16x8 af[4], bb[4];
#pragma unroll
            for (int i = 0; i < 4; ++i) {
                int ra = wm * 64 + i * 16 + rsel;
                af[i] = *(const bf16x8*)&Ac[ra * 64 + ((kk * 4 + csrcf) ^ (ra & 7)) * 8];
                int rb = i * 16 + rsel;
                bb[i] = *(const bf16x8*)&Bc[rb * 64 + ((kk * 4 + csrcf) ^ (rb & 7)) * 8];
            }
#pragma unroll
            for (int i = 0; i < 4; ++i)
#pragma unroll
                for (int j = 0; j < 4; ++j)
                    acc[i][j] = __builtin_amdgcn_mfma_f32_16x16x32_bf16(af[i], bb[j], acc[i][j], 0, 0, 0);
        }
        cur ^= 1;
    }

    // ---- epilogue: up-waves export u (bf16) via LDS; gate-waves apply silu(g)*u
    const int c = lane & 15, rbase = (lane >> 4) * 4;
    const int obase = offsets[e];
    __syncthreads();                    // all staging reads done; safe to alias LDS
    if (wu) {
#pragma unroll
        for (int i = 0; i < 4; ++i)
#pragma unroll
            for (int r = 0; r < 4; ++r) {
                int row64 = i * 16 + rbase + r;
#pragma unroll
                for (int j = 0; j < 4; ++j)
                    ex[wm * 4096 + row64 * 64 + j * 16 + c] = f2bf(acc[i][j][r]);
            }
    }
    __syncthreads();
    if (!wu) {
#pragma unroll
        for (int i = 0; i < 4; ++i) {
#pragma unroll
            for (int r = 0; r < 4; ++r) {
                int row64 = i * 16 + rbase + r;
                int lrow = mtile * 128 + wm * 64 + row64;
                if (lrow < cnt) {
                    size_t orow = (size_t)(obase + lrow);
#pragma unroll
                    for (int j = 0; j < 4; ++j) {
                        float g = acc[i][j][r];
                        float u = bf2f(ex[wm * 4096 + row64 * 64 + j * 16 + c]);
                        float h = g * u / (1.f + __expf(-g));
                        Hbuf[orow * HDIM + n0 + j * 16 + c] = f2bf(h);
                    }
                }
            }
        }
    }
}

// ---------------- GEMM2: y[tok] += w * (hidden @ WdT^T)
// 2-phase double-buffered, BK=64, XOR-swizzled LDS (c ^= row&7), K split x2,
// compact tile-list grid.  (R5-proven inner loop.)
__global__ __launch_bounds__(256, 2)
void gemm2_kernel(const unsigned short* __restrict__ Hbuf,
                  const unsigned short* __restrict__ WdT,
                  float* __restrict__ y,
                  const int* __restrict__ offsets, const int* __restrict__ counts,
                  const int* __restrict__ row_tok, const float* __restrict__ row_w,
                  const int* __restrict__ tl_e, const int* __restrict__ tl_m) {
    const int slot = blockIdx.y;
    const int e = tl_e[slot];
    if (e < 0) return;
    const int mtile = tl_m[slot];
    const int kc = blockIdx.z;
    const int cnt = counts[e];
    const int n0 = blockIdx.x * 128;
    const int row0 = offsets[e] + mtile * 128;

    __shared__ unsigned short As[2][128 * 64];   // 32 KB
    __shared__ unsigned short Bs[2][128 * 64];   // 32 KB

    const int tid = threadIdx.x;
    const int lane = tid & 63;
    const int wave = tid >> 6;
    const int wm = wave >> 1, wn = wave & 1;

    f32x4 acc[4][4];
#pragma unroll
    for (int i = 0; i < 4; ++i)
#pragma unroll
        for (int j = 0; j < 4; ++j) acc[i][j] = (f32x4){0.f, 0.f, 0.f, 0.f};

    const int srow0 = tid >> 3;          // row within 32-row quarter (+i*32)
    const int sc0 = tid & 7;             // LDS 16B-chunk within 128B row
    const unsigned short* Aab = Hbuf + (size_t)row0 * HDIM;
    const unsigned short* Bbb = WdT + (size_t)e * DIM * HDIM + (size_t)n0 * HDIM;

    auto stage = [&](int buf, int kt) {
#pragma unroll
        for (int i = 0; i < 4; ++i) {
            int row = i * 32 + srow0;
            int csrc = sc0 ^ (row & 7);
            size_t go = (size_t)row * HDIM + kt + csrc * 8;
            int lo = (i * 256 + tid) * 8;
            gload16(Aab + go, &As[buf][lo]);
            gload16(Bbb + go, &Bs[buf][lo]);
        }
    };

    const int rsel = lane & 15;
    const int csrcf = lane >> 4;

    const int kbeg = kc * (HDIM / 2);
    const int kend = kbeg + (HDIM / 2);

    stage(0, kbeg);
    int cur = 0;
    for (int kt = kbeg; kt < kend; kt += 64) {
        __syncthreads();
        if (kt + 64 < kend) stage(cur ^ 1, kt + 64);
        const unsigned short* Ac = As[cur];
        const unsigned short* Bc = Bs[cur];
#pragma unroll
        for (int kk = 0; kk < 2; ++kk) {
            bf16x8 af[4], bf[4];
#pragma unroll
            for (int i = 0; i < 4; ++i) {
                int ra = wm * 64 + i * 16 + rsel;
                af[i] = *(const bf16x8*)&Ac[ra * 64 + ((kk * 4 + csrcf) ^ (ra & 7)) * 8];
                int rb = wn * 64 + i * 16 + rsel;
                bf[i] = *(const bf16x8*)&Bc[rb * 64 + ((kk * 4 + csrcf) ^ (rb & 7)) * 8];
            }
#pragma unroll
            for (int i = 0; i < 4; ++i)
#pragma unroll
                for (int j = 0; j < 4; ++j)
                    acc[i][j] = __builtin_amdgcn_mfma_f32_16x16x32_bf16(af[i], bf[j], acc[i][j], 0, 0, 0);
        }
        cur ^= 1;
    }

    const int c = lane & 15, rbase = (lane >> 4) * 4;
    const int obase = offsets[e];
#pragma unroll
    for (int i = 0; i < 4; ++i) {
#pragma unroll
        for (int r = 0; r < 4; ++r) {
            int lrow = mtile * 128 + wm * 64 + i * 16 + rbase + r;
            if (lrow < cnt) {
                int grow = obase + lrow;
                int tok = row_tok[grow];
                float w = row_w[grow];
#pragma unroll
                for (int j = 0; j < 4; ++j) {
                    atomicAdd(&y[(size_t)tok * DIM + n0 + wn * 64 + j * 16 + c], w * acc[i][j][r]);
                }
            }
        }
    }
}

extern "C" void kernel_launch(void* const* d_in, const int* in_sizes, int n_in,
                              void* d_out, int out_size, void* d_ws, size_t ws_size,
                              hipStream_t stream) {
    const float* x  = (const float*)d_in[0];
    const float* rw = (const float*)d_in[1];
    const float* gw = (const float*)d_in[2];
    const float* uw = (const float*)d_in[3];
    const float* dw = (const float*)d_in[4];
    float* y = (float*)d_out;

    char* ws = (char*)d_ws;
    int*   counts  = (int*)(ws + 0);
    int*   cursors = (int*)(ws + 32);
    int*   offsets = (int*)(ws + 64);
    int*   top_idx = (int*)(ws + 128);
    float* top_w   = (float*)(ws + 128 + 16384);
    int*   row_tok = (int*)(ws + 128 + 32768);
    float* row_w   = (float*)(ws + 128 + 32768 + 16896);
    int*   tl_e    = (int*)(ws + 128 + 32768 + 2 * 16896);
    int*   tl_m    = (int*)(ws + 128 + 32768 + 2 * 16896 + 256);
    size_t off = 128 + 32768 + 2 * 16896 + 512;
    off = (off + 255) & ~(size_t)255;
    unsigned short* Abuf = (unsigned short*)(ws + off); off += (size_t)ROWS_PAD * DIM * 2;
    unsigned short* Hbuf = (unsigned short*)(ws + off); off += (size_t)ROWS_PAD * HDIM * 2;
    unsigned short* WgT  = (unsigned short*)(ws + off); off += (size_t)NE * DIM * HDIM * 2;
    unsigned short* WuT  = (unsigned short*)(ws + off); off += (size_t)NE * DIM * HDIM * 2;
    unsigned short* WdT  = (unsigned short*)(ws + off); off += (size_t)NE * DIM * HDIM * 2;
    if (ws_size < off) return;  // workspace too small: fail loudly (zero output)

    hipMemsetAsync(counts, 0, 32, stream);
    hipMemsetAsync(d_out, 0, (size_t)out_size * 4, stream);

    prep_kernel<<<NTT + T_TOK / 4, 256, 0, stream>>>(gw, uw, dw, WgT, WuT, WdT,
                                                     x, rw, counts, top_idx, top_w);
    scan_kernel<<<1, 64, 0, stream>>>(counts, offsets, cursors, tl_e, tl_m);
    gather_kernel<<<T_TOK, 256, 0, stream>>>(x, top_idx, top_w, cursors, row_tok, row_w, Abuf);

    gemm1_kernel<<<dim3(HDIM / 64, TSLOTS), 256, 0, stream>>>(Abuf, WgT, WuT, Hbuf,
                                                              offsets, counts, tl_e, tl_m);
    gemm2_kernel<<<dim3(DIM / 128, TSLOTS, 2), 256, 0, stream>>>(Hbuf, WdT, y, offsets, counts,
                                                                 row_tok, row_w, tl_e, tl_m);
}

// Round 12
// 249.079 us; speedup vs baseline: 1.1463x; 1.0331x over previous
//
#include <hip/hip_runtime.h>
#include <hip/hip_bf16.h>
#include <stdint.h>

#define T_TOK 2048
#define DIM   1024
#define HDIM  2048
#define NE    8
#define ROWS_PAD 4224   // 4096 routed rows + 128 pad for tile overrun
#define TSLOTS 40       // max live (expert,mtile) pairs: 32 + 7 = 39

typedef __attribute__((ext_vector_type(8))) short bf16x8;
typedef __attribute__((ext_vector_type(8))) unsigned short u16x8;
typedef __attribute__((ext_vector_type(4))) float f32x4;

__device__ __forceinline__ unsigned short f2bf(float f) {
    union { float f; unsigned int u; } v; v.f = f;
    unsigned int r = v.u + 0x7FFF + ((v.u >> 16) & 1);   // round-nearest-even
    return (unsigned short)(r >> 16);
}

__device__ __forceinline__ float bf2f(unsigned short b) {
    union { unsigned int u; float f; } v; v.u = ((unsigned int)b) << 16;
    return v.f;
}

__device__ __forceinline__ void gload16(const void* g, void* l) {
    __builtin_amdgcn_global_load_lds(
        (const __attribute__((address_space(1))) void*)g,
        (__attribute__((address_space(3))) void*)l, 16, 0, 0);
}

// ---------------- router: logits = x @ rw, top-2 softmax, counts
__global__ void router_kernel(const float* __restrict__ x, const float* __restrict__ rw,
                              int* __restrict__ counts, int* __restrict__ top_idx,
                              float* __restrict__ top_w) {
    int wid = (blockIdx.x * blockDim.x + threadIdx.x) >> 6;
    int lane = threadIdx.x & 63;
    if (wid >= T_TOK) return;
    float acc[NE];
#pragma unroll
    for (int e = 0; e < NE; ++e) acc[e] = 0.f;
    const float* xr = x + (size_t)wid * DIM;
    for (int i = lane; i < DIM; i += 64) {
        float xv = xr[i];
        const float* wr = rw + (size_t)i * NE;
#pragma unroll
        for (int e = 0; e < NE; ++e) acc[e] += xv * wr[e];
    }
#pragma unroll
    for (int off = 32; off; off >>= 1) {
#pragma unroll
        for (int e = 0; e < NE; ++e) acc[e] += __shfl_xor(acc[e], off, 64);
    }
    if (lane == 0) {
        float v0 = -1e30f, v1 = -1e30f; int i0 = 0, i1 = 0;
#pragma unroll
        for (int e = 0; e < NE; ++e) {
            float v = acc[e];
            if (v > v0) { v1 = v0; i1 = i0; v0 = v; i0 = e; }
            else if (v > v1) { v1 = v; i1 = e; }
        }
        float e1 = __expf(v1 - v0);
        float s = 1.f + e1;
        top_idx[wid * 2]     = i0;
        top_idx[wid * 2 + 1] = i1;
        top_w[wid * 2]     = 1.f / s;
        top_w[wid * 2 + 1] = e1 / s;
        atomicAdd(&counts[i0], 1);
        atomicAdd(&counts[i1], 1);
    }
}

// ---------------- scan + compact tile list (holes only at the tail)
__global__ void scan_kernel(const int* __restrict__ counts, int* __restrict__ offsets,
                            int* __restrict__ cursors,
                            int* __restrict__ tl_e, int* __restrict__ tl_m) {
    if (threadIdx.x == 0) {
        int run = 0;
        for (int e = 0; e < NE; ++e) { offsets[e] = run; cursors[e] = run; run += counts[e]; }
        int n = 0;
        for (int e = 0; e < NE; ++e) {
            int mt = (counts[e] + 127) >> 7;
            for (int m = 0; m < mt && n < 64; ++m) { tl_e[n] = e; tl_m[n] = m; ++n; }
        }
        for (; n < 64; ++n) tl_e[n] = -1;
    }
}

// ---------------- gather: pack each token's row (bf16) into its 2 experts' segments
__global__ void gather_kernel(const float* __restrict__ x, const int* __restrict__ top_idx,
                              const float* __restrict__ top_w, int* __restrict__ cursors,
                              int* __restrict__ row_tok, float* __restrict__ row_w,
                              unsigned short* __restrict__ Abuf) {
    int t = blockIdx.x;
    __shared__ int pos[2];
    if (threadIdx.x < 2) {
        int k = threadIdx.x;
        int e = top_idx[t * 2 + k];
        int p = atomicAdd(&cursors[e], 1);
        pos[k] = p;
        row_tok[p] = t;
        row_w[p] = top_w[t * 2 + k];
    }
    __syncthreads();
    const float4* xr = (const float4*)(x + (size_t)t * DIM);
    float4 v = xr[threadIdx.x];
    ushort4 b;
    b.x = f2bf(v.x); b.y = f2bf(v.y); b.z = f2bf(v.z); b.w = f2bf(v.w);
    ushort4* A4 = (ushort4*)Abuf;
    A4[(size_t)pos[0] * (DIM / 4) + threadIdx.x] = b;
    A4[(size_t)pos[1] * (DIM / 4) + threadIdx.x] = b;
}

// ---------------- GEMM1: hidden = silu(A @ Wg^T) * (A @ Wu^T), per expert
// BM=128, BN=64, BK=64; 4 waves = 2(m) x 2(gate|up); 64KB LDS double-buffered.
// B staged DIRECTLY from fp32 gw/uw (original [d][h] layout): strided lane-coalesced
// loads held in regs through MFMA (issue-early/write-late), cvt+ds_write into the
// same swizzled layout the fragment reads expect. A staged via global_load_lds.
__global__ __launch_bounds__(256, 2)
void gemm1_kernel(const unsigned short* __restrict__ Abuf,
                  const float* __restrict__ gw,
                  const float* __restrict__ uw,
                  unsigned short* __restrict__ Hbuf,
                  const int* __restrict__ offsets, const int* __restrict__ counts,
                  const int* __restrict__ tl_e, const int* __restrict__ tl_m) {
    const int slot = blockIdx.y;
    const int e = tl_e[slot];
    if (e < 0) return;
    const int mtile = tl_m[slot];
    const int cnt = counts[e];
    const int n0 = blockIdx.x * 64;
    const int row0 = offsets[e] + mtile * 128;

    __shared__ __align__(16) unsigned char lds_raw[65536];
    unsigned short* AsB = (unsigned short*)lds_raw;            // [2][128*64] = 32KB
    unsigned short* BgB = (unsigned short*)(lds_raw + 32768);  // [2][64*64]  = 16KB
    unsigned short* BuB = (unsigned short*)(lds_raw + 49152);  // [2][64*64]  = 16KB
    unsigned short* ex  = (unsigned short*)lds_raw;            // epilogue [2][64][64] bf16 (aliases AsB)

    const int tid = threadIdx.x;
    const int lane = tid & 63;
    const int wave = tid >> 6;
    const int wm = wave >> 1;        // m-half (0,1)
    const int wu = wave & 1;         // 0 = gate, 1 = up

    f32x4 acc[4][4];
#pragma unroll
    for (int i = 0; i < 4; ++i)
#pragma unroll
        for (int j = 0; j < 4; ++j) acc[i][j] = (f32x4){0.f, 0.f, 0.f, 0.f};

    // A staging: rows of 64 shorts = 8 x 16B chunks; physical chunk p holds global p^(row&7)
    const int srow = tid >> 3;          // 0..31
    const int sc0 = tid & 7;
    const unsigned short* Aab = Abuf + (size_t)row0 * DIM;

    auto stageA = [&](int buf, int kt) {
#pragma unroll
        for (int i = 0; i < 4; ++i) {                          // 128 rows
            int row = i * 32 + srow;
            int csrc = sc0 ^ (row & 7);
            gload16(Aab + (size_t)row * DIM + kt + csrc * 8,
                    AsB + buf * 8192 + (i * 256 + tid) * 8);
        }
    };

    // B staging: thread owns n = tid&63, chunks c = (tid>>6), (tid>>6)+4.
    // Loads: 8 k-consecutive fp32 at stride HDIM, lanes n-coalesced (256B/instr).
    const int bn = tid & 63;
    const int bc0 = tid >> 6;           // 0..3
    const float* Bgb = gw + (size_t)e * DIM * HDIM + n0 + bn;
    const float* Bub = uw + (size_t)e * DIM * HDIM + n0 + bn;

    float bgl[2][8], bul[2][8];
    auto bload = [&](int kt) {
#pragma unroll
        for (int cc = 0; cc < 2; ++cc) {
            int c = bc0 + cc * 4;
            const float* gs = Bgb + (size_t)(kt + c * 8) * HDIM;
            const float* us = Bub + (size_t)(kt + c * 8) * HDIM;
#pragma unroll
            for (int jj = 0; jj < 8; ++jj) {
                bgl[cc][jj] = gs[(size_t)jj * HDIM];
                bul[cc][jj] = us[(size_t)jj * HDIM];
            }
        }
    };
    auto bwrite = [&](int buf) {
#pragma unroll
        for (int cc = 0; cc < 2; ++cc) {
            int c = bc0 + cc * 4;
            int la = bn * 64 + ((c ^ (bn & 7)) * 8);
            u16x8 vg, vu;
#pragma unroll
            for (int jj = 0; jj < 8; ++jj) {
                vg[jj] = f2bf(bgl[cc][jj]);
                vu[jj] = f2bf(bul[cc][jj]);
            }
            *(u16x8*)&BgB[buf * 4096 + la] = vg;
            *(u16x8*)&BuB[buf * 4096 + la] = vu;
        }
    };

    const int rsel = lane & 15;
    const int csrcf = lane >> 4;        // fragment k-chunk (0..3)

    stageA(0, 0);
    bload(0);
    bwrite(0);
    int cur = 0;
    for (int kt = 0; kt < DIM; kt += 64) {
        __syncthreads();                // buf[cur] ready (A dma drained, B writes done)
        const bool pre = (kt + 64 < DIM);
        if (pre) { stageA(cur ^ 1, kt + 64); bload(kt + 64); }   // issue early
        const unsigned short* Ac = AsB + cur * 8192;
        const unsigned short* Bc = (wu ? BuB : BgB) + cur * 4096;
#pragma unroll
        for (int kk = 0; kk < 2; ++kk) {
            bf16x8 af[4], bb[4];
#pragma unroll
            for (int i = 0; i < 4; ++i) {
                int ra = wm * 64 + i * 16 + rsel;
                af[i] = *(const bf16x8*)&Ac[ra * 64 + ((kk * 4 + csrcf) ^ (ra & 7)) * 8];
                int rb = i * 16 + rsel;
                bb[i] = *(const bf16x8*)&Bc[rb * 64 + ((kk * 4 + csrcf) ^ (rb & 7)) * 8];
            }
#pragma unroll
            for (int i = 0; i < 4; ++i)
#pragma unroll
                for (int j = 0; j < 4; ++j)
                    acc[i][j] = __builtin_amdgcn_mfma_f32_16x16x32_bf16(af[i], bb[j], acc[i][j], 0, 0, 0);
        }
        if (pre) bwrite(cur ^ 1);       // write late (loads' latency hidden by MFMAs)
        cur ^= 1;
    }

    // ---- epilogue: up-waves export u (bf16) via LDS; gate-waves apply silu(g)*u
    const int c = lane & 15, rbase = (lane >> 4) * 4;
    const int obase = offsets[e];
    __syncthreads();                    // all staging reads done; safe to alias LDS
    if (wu) {
#pragma unroll
        for (int i = 0; i < 4; ++i)
#pragma unroll
            for (int r = 0; r < 4; ++r) {
                int row64 = i * 16 + rbase + r;
#pragma unroll
                for (int j = 0; j < 4; ++j)
                    ex[wm * 4096 + row64 * 64 + j * 16 + c] = f2bf(acc[i][j][r]);
            }
    }
    __syncthreads();
    if (!wu) {
#pragma unroll
        for (int i = 0; i < 4; ++i) {
#pragma unroll
            for (int r = 0; r < 4; ++r) {
                int row64 = i * 16 + rbase + r;
                int lrow = mtile * 128 + wm * 64 + row64;
                if (lrow < cnt) {
                    size_t orow = (size_t)(obase + lrow);
#pragma unroll
                    for (int j = 0; j < 4; ++j) {
                        float g = acc[i][j][r];
                        float u = bf2f(ex[wm * 4096 + row64 * 64 + j * 16 + c]);
                        float h = g * u / (1.f + __expf(-g));
                        Hbuf[orow * HDIM + n0 + j * 16 + c] = f2bf(h);
                    }
                }
            }
        }
    }
}

// ---------------- GEMM2: y[tok] += w * (hidden @ Wd^T)
// BM=128, BN=128, BK=64, K split x2. B staged DIRECTLY from fp32 dw ([h][d] layout):
// contraction k=h strided, n=d lane-coalesced. A (Hbuf) via global_load_lds.
__global__ __launch_bounds__(256, 2)
void gemm2_kernel(const unsigned short* __restrict__ Hbuf,
                  const float* __restrict__ dw,
                  float* __restrict__ y,
                  const int* __restrict__ offsets, const int* __restrict__ counts,
                  const int* __restrict__ row_tok, const float* __restrict__ row_w,
                  const int* __restrict__ tl_e, const int* __restrict__ tl_m) {
    const int slot = blockIdx.y;
    const int e = tl_e[slot];
    if (e < 0) return;
    const int mtile = tl_m[slot];
    const int kc = blockIdx.z;
    const int cnt = counts[e];
    const int n0 = blockIdx.x * 128;
    const int row0 = offsets[e] + mtile * 128;

    __shared__ unsigned short As[2][128 * 64];   // 32 KB
    __shared__ unsigned short Bs[2][128 * 64];   // 32 KB

    const int tid = threadIdx.x;
    const int lane = tid & 63;
    const int wave = tid >> 6;
    const int wm = wave >> 1, wn = wave & 1;

    f32x4 acc[4][4];
#pragma unroll
    for (int i = 0; i < 4; ++i)
#pragma unroll
        for (int j = 0; j < 4; ++j) acc[i][j] = (f32x4){0.f, 0.f, 0.f, 0.f};

    const int srow0 = tid >> 3;
    const int sc0 = tid & 7;
    const unsigned short* Aab = Hbuf + (size_t)row0 * HDIM;

    auto stageA = [&](int buf, int kt) {
#pragma unroll
        for (int i = 0; i < 4; ++i) {
            int row = i * 32 + srow0;
            int csrc = sc0 ^ (row & 7);
            gload16(Aab + (size_t)row * HDIM + kt + csrc * 8,
                    &As[buf][(i * 256 + tid) * 8]);
        }
    };

    // B staging: thread owns n = tid&127, chunks c = (tid>>7)*4 + 0..3.
    const int bn = tid & 127;
    const int bc0 = (tid >> 7) * 4;     // 0 or 4
    const float* Bbb = dw + (size_t)e * HDIM * DIM + n0 + bn;

    float bl[4][8];
    auto bload = [&](int kt) {
#pragma unroll
        for (int cc = 0; cc < 4; ++cc) {
            const float* bs = Bbb + (size_t)(kt + (bc0 + cc) * 8) * DIM;
#pragma unroll
            for (int jj = 0; jj < 8; ++jj)
                bl[cc][jj] = bs[(size_t)jj * DIM];
        }
    };
    auto bwrite = [&](int buf) {
#pragma unroll
        for (int cc = 0; cc < 4; ++cc) {
            int c = bc0 + cc;
            int la = bn * 64 + ((c ^ (bn & 7)) * 8);
            u16x8 v;
#pragma unroll
            for (int jj = 0; jj < 8; ++jj) v[jj] = f2bf(bl[cc][jj]);
            *(u16x8*)&Bs[buf][la] = v;
        }
    };

    const int rsel = lane & 15;
    const int csrcf = lane >> 4;

    const int kbeg = kc * (HDIM / 2);
    const int kend = kbeg + (HDIM / 2);

    stageA(0, kbeg);
    bload(kbeg);
    bwrite(0);
    int cur = 0;
    for (int kt = kbeg; kt < kend; kt += 64) {
        __syncthreads();
        const bool pre = (kt + 64 < kend);
        if (pre) { stageA(cur ^ 1, kt + 64); bload(kt + 64); }
        const unsigned short* Ac = As[cur];
        const unsigned short* Bc = Bs[cur];
#pragma unroll
        for (int kk = 0; kk < 2; ++kk) {
            bf16x8 af[4], bf[4];
#pragma unroll
            for (int i = 0; i < 4; ++i) {
                int ra = wm * 64 + i * 16 + rsel;
                af[i] = *(const bf16x8*)&Ac[ra * 64 + ((kk * 4 + csrcf) ^ (ra & 7)) * 8];
                int rb = wn * 64 + i * 16 + rsel;
                bf[i] = *(const bf16x8*)&Bc[rb * 64 + ((kk * 4 + csrcf) ^ (rb & 7)) * 8];
            }
#pragma unroll
            for (int i = 0; i < 4; ++i)
#pragma unroll
                for (int j = 0; j < 4; ++j)
                    acc[i][j] = __builtin_amdgcn_mfma_f32_16x16x32_bf16(af[i], bf[j], acc[i][j], 0, 0, 0);
        }
        if (pre) bwrite(cur ^ 1);
        cur ^= 1;
    }

    const int c = lane & 15, rbase = (lane >> 4) * 4;
    const int obase = offsets[e];
#pragma unroll
    for (int i = 0; i < 4; ++i) {
#pragma unroll
        for (int r = 0; r < 4; ++r) {
            int lrow = mtile * 128 + wm * 64 + i * 16 + rbase + r;
            if (lrow < cnt) {
                int grow = obase + lrow;
                int tok = row_tok[grow];
                float w = row_w[grow];
#pragma unroll
                for (int j = 0; j < 4; ++j) {
                    atomicAdd(&y[(size_t)tok * DIM + n0 + wn * 64 + j * 16 + c], w * acc[i][j][r]);
                }
            }
        }
    }
}

extern "C" void kernel_launch(void* const* d_in, const int* in_sizes, int n_in,
                              void* d_out, int out_size, void* d_ws, size_t ws_size,
                              hipStream_t stream) {
    const float* x  = (const float*)d_in[0];
    const float* rw = (const float*)d_in[1];
    const float* gw = (const float*)d_in[2];
    const float* uw = (const float*)d_in[3];
    const float* dw = (const float*)d_in[4];
    float* y = (float*)d_out;

    char* ws = (char*)d_ws;
    int*   counts  = (int*)(ws + 0);
    int*   cursors = (int*)(ws + 32);
    int*   offsets = (int*)(ws + 64);
    int*   top_idx = (int*)(ws + 128);
    float* top_w   = (float*)(ws + 128 + 16384);
    int*   row_tok = (int*)(ws + 128 + 32768);
    float* row_w   = (float*)(ws + 128 + 32768 + 16896);
    int*   tl_e    = (int*)(ws + 128 + 32768 + 2 * 16896);
    int*   tl_m    = (int*)(ws + 128 + 32768 + 2 * 16896 + 256);
    size_t off = 128 + 32768 + 2 * 16896 + 512;
    off = (off + 255) & ~(size_t)255;
    unsigned short* Abuf = (unsigned short*)(ws + off); off += (size_t)ROWS_PAD * DIM * 2;
    unsigned short* Hbuf = (unsigned short*)(ws + off); off += (size_t)ROWS_PAD * HDIM * 2;
    if (ws_size < off) return;  // workspace too small: fail loudly (zero output)

    hipMemsetAsync(counts, 0, 32, stream);
    hipMemsetAsync(d_out, 0, (size_t)out_size * 4, stream);

    router_kernel<<<T_TOK / 4, 256, 0, stream>>>(x, rw, counts, top_idx, top_w);
    scan_kernel<<<1, 64, 0, stream>>>(counts, offsets, cursors, tl_e, tl_m);
    gather_kernel<<<T_TOK, 256, 0, stream>>>(x, top_idx, top_w, cursors, row_tok, row_w, Abuf);

    gemm1_kernel<<<dim3(HDIM / 64, TSLOTS), 256, 0, stream>>>(Abuf, gw, uw, Hbuf,
                                                              offsets, counts, tl_e, tl_m);
    gemm2_kernel<<<dim3(DIM / 128, TSLOTS, 2), 256, 0, stream>>>(Hbuf, dw, y, offsets, counts,
                                                                 row_tok, row_w, tl_e, tl_m);
}